// Round 1
// baseline (2998.712 us; speedup 1.0000x reference)
//
#include <hip/hip_runtime.h>
#include <math.h>

#define NGRAPHS 8

// ---------------------------------------------------------------------------
// GEMM: out[n][o] = sum_i f(in[n][i]) * W[o][i] + b[o]   (f = tanh if TANH)
// Block = 256 threads, 16 nodes/block. W^T staged in LDS (+1 pad -> only
// free 2-way conflicts), input tile in LDS.
// ---------------------------------------------------------------------------
template<bool TANH>
__global__ __launch_bounds__(256) void gemm_kernel(
    const float* __restrict__ in, const float* __restrict__ W,
    const float* __restrict__ bias, float* __restrict__ out)
{
    __shared__ float Wt[64 * 65];   // Wt[i*65 + o] = W[o][i]
    __shared__ float xs[16 * 65];   // xs[nl*65 + i]
    const int t = threadIdx.x;
    const int node0 = blockIdx.x * 16;

    // stage W transposed (coalesced global read; (i+o)%32 banks -> no conflict)
    #pragma unroll
    for (int k = 0; k < 16; ++k) {
        int idx = k * 256 + t;          // 4096 elements
        int o = idx >> 6, i = idx & 63;
        Wt[i * 65 + o] = W[idx];
    }
    // stage input tile (1024 elements), fuse tanh
    #pragma unroll
    for (int k = 0; k < 4; ++k) {
        int idx = k * 256 + t;
        int nl = idx >> 6, i = idx & 63;
        float v = in[node0 * 64 + idx];
        if (TANH) v = tanhf(v);
        xs[nl * 65 + i] = v;
    }
    __syncthreads();

    const int nl = t >> 4;   // node within tile, 0..15
    const int o4 = t & 15;   // output quad, o = o4*4 .. o4*4+3
    float4 acc = make_float4(0.f, 0.f, 0.f, 0.f);
    #pragma unroll
    for (int i = 0; i < 64; ++i) {
        float xv = xs[nl * 65 + i];            // broadcast within 16-lane group
        const float* wr = &Wt[i * 65 + o4 * 4]; // 2-way bank alias only (free)
        acc.x += xv * wr[0];
        acc.y += xv * wr[1];
        acc.z += xv * wr[2];
        acc.w += xv * wr[3];
    }
    float4 b4 = ((const float4*)bias)[o4];
    acc.x += b4.x; acc.y += b4.y; acc.z += b4.z; acc.w += b4.w;
    ((float4*)out)[(node0 + nl) * 16 + o4] = acc;
}

// ---------------------------------------------------------------------------
// Edge scatter: out[dst[e]] += m[src[e]]  (64 floats/edge)
// 16 threads per edge, float4 each -> coalesced 256B row gather.
// ---------------------------------------------------------------------------
__global__ __launch_bounds__(256) void scatter_kernel(
    const float* __restrict__ m, const int* __restrict__ src,
    const int* __restrict__ dst, float* __restrict__ out, int E)
{
    int gid = blockIdx.x * 256 + threadIdx.x;
    int e = gid >> 4;
    if (e >= E) return;
    int c = gid & 15;
    int s = src[e], d = dst[e];
    float4 v = ((const float4*)m)[s * 16 + c];
    float* o = out + (size_t)d * 64 + c * 4;
    unsafeAtomicAdd(o + 0, v.x);
    unsafeAtomicAdd(o + 1, v.y);
    unsafeAtomicAdd(o + 2, v.z);
    unsafeAtomicAdd(o + 3, v.w);
}

// ---------------------------------------------------------------------------
// w3s[i] = sum_o W3[o][i];  w3s[64] = sum(b3)   (single tiny block)
// ---------------------------------------------------------------------------
__global__ void w3s_kernel(const float* __restrict__ W3,
                           const float* __restrict__ b3,
                           float* __restrict__ w3s)
{
    int i = threadIdx.x;   // 64 threads
    float s = 0.f;
    for (int o = 0; o < 64; ++o) s += W3[o * 64 + i];
    w3s[i] = s;
    if (i == 0) {
        float bs = 0.f;
        for (int k = 0; k < 64; ++k) bs += b3[k];
        w3s[64] = bs;
    }
}

// ---------------------------------------------------------------------------
// s3[n] = tanh(agg[n]) . w3s + w3s[64]   (layer-3 collapsed to a dot)
// 256 threads = 64 nodes/block, 4 lanes per node, shuffle-reduce.
// ---------------------------------------------------------------------------
__global__ __launch_bounds__(256) void s3_kernel(
    const float* __restrict__ agg, const float* __restrict__ w3s,
    float* __restrict__ s3, int N)
{
    int t = threadIdx.x;
    int nl = t >> 2, q = t & 3;
    int node = blockIdx.x * 64 + nl;
    float partial = 0.f;
    if (node < N) {
        const float4* a4 = (const float4*)agg;
        const float4* w4 = (const float4*)w3s;
        #pragma unroll
        for (int k = 0; k < 4; ++k) {
            float4 v = a4[(size_t)node * 16 + q * 4 + k];
            float4 w = w4[q * 4 + k];
            partial += tanhf(v.x) * w.x + tanhf(v.y) * w.y
                     + tanhf(v.z) * w.z + tanhf(v.w) * w.w;
        }
    }
    partial += __shfl_down(partial, 1);
    partial += __shfl_down(partial, 2);
    if (q == 0 && node < N) s3[node] = partial + w3s[64];
}

// ---------------------------------------------------------------------------
// per_graph[n2g[dst[e]]] += s3[src[e]]  -- LDS 8-bin reduce then 8 global
// atomics per block.
// ---------------------------------------------------------------------------
__global__ __launch_bounds__(256) void graph_reduce_kernel(
    const float* __restrict__ s3, const int* __restrict__ src,
    const int* __restrict__ dst, const int* __restrict__ n2g,
    float* __restrict__ out, int E)
{
    __shared__ float bins[NGRAPHS];
    int t = threadIdx.x;
    if (t < NGRAPHS) bins[t] = 0.f;
    __syncthreads();
    int e = blockIdx.x * 256 + t;
    if (e < E) {
        float v = s3[src[e]];
        int g = n2g[dst[e]];
        atomicAdd(&bins[g], v);
    }
    __syncthreads();
    if (t < NGRAPHS) unsafeAtomicAdd(&out[t], bins[t]);
}

// ---------------------------------------------------------------------------
extern "C" void kernel_launch(void* const* d_in, const int* in_sizes, int n_in,
                              void* d_out, int out_size, void* d_ws, size_t ws_size,
                              hipStream_t stream)
{
    const float* x   = (const float*)d_in[0];
    const float* W1  = (const float*)d_in[1];
    const float* b1  = (const float*)d_in[2];
    const float* W2  = (const float*)d_in[3];
    const float* b2  = (const float*)d_in[4];
    const float* W3  = (const float*)d_in[5];
    const float* b3  = (const float*)d_in[6];
    const int*   src = (const int*)d_in[7];
    const int*   dst = (const int*)d_in[8];
    const int*   n2g = (const int*)d_in[9];

    const int N = in_sizes[0] / 64;   // 100000
    const int E = in_sizes[7];        // 1600000

    float* A   = (float*)d_ws;                 // [N*64] layer output m
    float* B   = A + (size_t)N * 64;           // [N*64] aggregation target
    float* s3b = B + (size_t)N * 64;           // [N]
    float* w3s = s3b + N;                      // [65] (offset stays 16B-aligned)
    float* out = (float*)d_out;

    const int gemm_blocks    = N / 16;                 // 6250
    const int scatter_blocks = (E * 16 + 255) / 256;   // 100000
    const size_t aggBytes = (size_t)N * 64 * sizeof(float);

    // Layer 1
    gemm_kernel<false><<<gemm_blocks, 256, 0, stream>>>(x, W1, b1, A);
    hipMemsetAsync(B, 0, aggBytes, stream);
    scatter_kernel<<<scatter_blocks, 256, 0, stream>>>(A, src, dst, B, E);

    // Layer 2 (tanh fused into GEMM input load)
    gemm_kernel<true><<<gemm_blocks, 256, 0, stream>>>(B, W2, b2, A);
    hipMemsetAsync(B, 0, aggBytes, stream);
    scatter_kernel<<<scatter_blocks, 256, 0, stream>>>(A, src, dst, B, E);

    // Layer 3 collapsed: s3[n] = tanh(agg2[n]) . colsum(W3) + sum(b3),
    // then per-edge graph reduction.
    w3s_kernel<<<1, 64, 0, stream>>>(W3, b3, w3s);
    s3_kernel<<<(N + 63) / 64, 256, 0, stream>>>(B, w3s, s3b, N);
    hipMemsetAsync(out, 0, NGRAPHS * sizeof(float), stream);
    graph_reduce_kernel<<<(E + 255) / 256, 256, 0, stream>>>(s3b, src, dst, n2g, out, E);
}

// Round 2
// 532.009 us; speedup vs baseline: 5.6366x; 5.6366x over previous
//
#include <hip/hip_runtime.h>
#include <math.h>

#define NGRAPHS 8

// ---------------------------------------------------------------------------
// GEMM: out[n][o] = sum_i f(in[n][i]) * W[o][i] + b[o]   (f = tanh if TANH)
// Block = 256 threads, 16 nodes/block. W^T staged in LDS (+1 pad).
// (verified absmax 0 in round 1 — unchanged)
// ---------------------------------------------------------------------------
template<bool TANH>
__global__ __launch_bounds__(256) void gemm_kernel(
    const float* __restrict__ in, const float* __restrict__ W,
    const float* __restrict__ bias, float* __restrict__ out)
{
    __shared__ float Wt[64 * 65];   // Wt[i*65 + o] = W[o][i]
    __shared__ float xs[16 * 65];   // xs[nl*65 + i]
    const int t = threadIdx.x;
    const int node0 = blockIdx.x * 16;

    #pragma unroll
    for (int k = 0; k < 16; ++k) {
        int idx = k * 256 + t;
        int o = idx >> 6, i = idx & 63;
        Wt[i * 65 + o] = W[idx];
    }
    #pragma unroll
    for (int k = 0; k < 4; ++k) {
        int idx = k * 256 + t;
        int nl = idx >> 6, i = idx & 63;
        float v = in[node0 * 64 + idx];
        if (TANH) v = tanhf(v);
        xs[nl * 65 + i] = v;
    }
    __syncthreads();

    const int nl = t >> 4;
    const int o4 = t & 15;
    float4 acc = make_float4(0.f, 0.f, 0.f, 0.f);
    #pragma unroll
    for (int i = 0; i < 64; ++i) {
        float xv = xs[nl * 65 + i];
        const float* wr = &Wt[i * 65 + o4 * 4];
        acc.x += xv * wr[0];
        acc.y += xv * wr[1];
        acc.z += xv * wr[2];
        acc.w += xv * wr[3];
    }
    float4 b4 = ((const float4*)bias)[o4];
    acc.x += b4.x; acc.y += b4.y; acc.z += b4.z; acc.w += b4.w;
    ((float4*)out)[(node0 + nl) * 16 + o4] = acc;
}

// ---------------------------------------------------------------------------
// CSR build: histogram of dst
// ---------------------------------------------------------------------------
__global__ __launch_bounds__(256) void hist_kernel(
    const int* __restrict__ dst, int* __restrict__ counts, int E)
{
    int e = blockIdx.x * 256 + threadIdx.x;
    if (e < E) atomicAdd(&counts[dst[e]], 1);
}

// per-block exclusive scan; block totals -> bsums
__global__ __launch_bounds__(256) void scan1_kernel(
    const int* __restrict__ counts, int* __restrict__ exc,
    int* __restrict__ bsums, int N)
{
    __shared__ int tmp[256];
    int t = threadIdx.x;
    int i = blockIdx.x * 256 + t;
    int v = (i < N) ? counts[i] : 0;
    tmp[t] = v;
    __syncthreads();
    #pragma unroll
    for (int off = 1; off < 256; off <<= 1) {
        int u = (t >= off) ? tmp[t - off] : 0;
        __syncthreads();
        tmp[t] += u;
        __syncthreads();
    }
    if (i < N) exc[i] = tmp[t] - v;          // exclusive
    if (t == 255) bsums[blockIdx.x] = tmp[255];
}

// single-block exclusive scan of block sums (nb <= 512)
__global__ __launch_bounds__(512) void scan2_kernel(int* __restrict__ bsums, int nb)
{
    __shared__ int tmp[512];
    int t = threadIdx.x;
    int v = (t < nb) ? bsums[t] : 0;
    tmp[t] = v;
    __syncthreads();
    #pragma unroll
    for (int off = 1; off < 512; off <<= 1) {
        int u = (t >= off) ? tmp[t - off] : 0;
        __syncthreads();
        tmp[t] += u;
        __syncthreads();
    }
    if (t < nb) bsums[t] = tmp[t] - v;       // exclusive
}

__global__ __launch_bounds__(256) void scan3_kernel(
    const int* __restrict__ exc, const int* __restrict__ bsums,
    int* __restrict__ rowptr, int N, int E)
{
    int i = blockIdx.x * 256 + threadIdx.x;
    if (i < N) rowptr[i] = exc[i] + bsums[blockIdx.x];
    if (i == 0) rowptr[N] = E;
}

// bucket-scatter src ids into CSR order
__global__ __launch_bounds__(256) void build_kernel(
    const int* __restrict__ src, const int* __restrict__ dst,
    const int* __restrict__ rowptr, int* __restrict__ cursor,
    int* __restrict__ esrc, int E)
{
    int e = blockIdx.x * 256 + threadIdx.x;
    if (e >= E) return;
    int d = dst[e];
    int pos = atomicAdd(&cursor[d], 1);
    esrc[rowptr[d] + pos] = src[e];
}

// ---------------------------------------------------------------------------
// Gather-aggregate: out[n] = sum_{e in in(n)} m[esrc[e]]   (64 floats/node)
// 16 threads per node, float4 each -> each edge row read is a coalesced 256B.
// Zero atomics, one clean 256B store per node.
// ---------------------------------------------------------------------------
__global__ __launch_bounds__(256) void gather_agg_kernel(
    const float* __restrict__ m, const int* __restrict__ esrc,
    const int* __restrict__ rowptr, float* __restrict__ out, int N)
{
    int gid = blockIdx.x * 256 + threadIdx.x;
    int n = gid >> 4;
    if (n >= N) return;
    int c = gid & 15;
    int beg = rowptr[n], end = rowptr[n + 1];
    float4 acc = make_float4(0.f, 0.f, 0.f, 0.f);
    for (int e = beg; e < end; ++e) {
        int s = esrc[e];                       // wave-uniform within 16-group
        float4 v = ((const float4*)m)[(size_t)s * 16 + c];
        acc.x += v.x; acc.y += v.y; acc.z += v.z; acc.w += v.w;
    }
    ((float4*)out)[(size_t)n * 16 + c] = acc;
}

// ---------------------------------------------------------------------------
// w3s[i] = sum_o W3[o][i];  w3s[64] = sum(b3)
// ---------------------------------------------------------------------------
__global__ void w3s_kernel(const float* __restrict__ W3,
                           const float* __restrict__ b3,
                           float* __restrict__ w3s)
{
    int i = threadIdx.x;   // 64 threads
    float s = 0.f;
    for (int o = 0; o < 64; ++o) s += W3[o * 64 + i];
    w3s[i] = s;
    if (i == 0) {
        float bs = 0.f;
        for (int k = 0; k < 64; ++k) bs += b3[k];
        w3s[64] = bs;
    }
}

// ---------------------------------------------------------------------------
// s3[n] = tanh(agg[n]) . w3s + w3s[64]
// ---------------------------------------------------------------------------
__global__ __launch_bounds__(256) void s3_kernel(
    const float* __restrict__ agg, const float* __restrict__ w3s,
    float* __restrict__ s3, int N)
{
    int t = threadIdx.x;
    int nl = t >> 2, q = t & 3;
    int node = blockIdx.x * 64 + nl;
    float partial = 0.f;
    if (node < N) {
        const float4* a4 = (const float4*)agg;
        const float4* w4 = (const float4*)w3s;
        #pragma unroll
        for (int k = 0; k < 4; ++k) {
            float4 v = a4[(size_t)node * 16 + q * 4 + k];
            float4 w = w4[q * 4 + k];
            partial += tanhf(v.x) * w.x + tanhf(v.y) * w.y
                     + tanhf(v.z) * w.z + tanhf(v.w) * w.w;
        }
    }
    partial += __shfl_down(partial, 1);
    partial += __shfl_down(partial, 2);
    if (q == 0 && node < N) s3[node] = partial + w3s[64];
}

// ---------------------------------------------------------------------------
// per_graph[n2g[n]] += sum_{e in in(n)} s3[esrc[e]]   via CSR, LDS bins.
// ---------------------------------------------------------------------------
__global__ __launch_bounds__(256) void graph_reduce_kernel(
    const float* __restrict__ s3, const int* __restrict__ esrc,
    const int* __restrict__ rowptr, const int* __restrict__ n2g,
    float* __restrict__ out, int N)
{
    __shared__ float bins[NGRAPHS];
    int t = threadIdx.x;
    if (t < NGRAPHS) bins[t] = 0.f;
    __syncthreads();
    int n = blockIdx.x * 256 + t;
    if (n < N) {
        float acc = 0.f;
        for (int e = rowptr[n]; e < rowptr[n + 1]; ++e) acc += s3[esrc[e]];
        atomicAdd(&bins[n2g[n]], acc);
    }
    __syncthreads();
    if (t < NGRAPHS) unsafeAtomicAdd(&out[t], bins[t]);
}

// ---------------------------------------------------------------------------
extern "C" void kernel_launch(void* const* d_in, const int* in_sizes, int n_in,
                              void* d_out, int out_size, void* d_ws, size_t ws_size,
                              hipStream_t stream)
{
    const float* x   = (const float*)d_in[0];
    const float* W1  = (const float*)d_in[1];
    const float* b1  = (const float*)d_in[2];
    const float* W2  = (const float*)d_in[3];
    const float* b2  = (const float*)d_in[4];
    const float* W3  = (const float*)d_in[5];
    const float* b3  = (const float*)d_in[6];
    const int*   src = (const int*)d_in[7];
    const int*   dst = (const int*)d_in[8];
    const int*   n2g = (const int*)d_in[9];

    const int N = in_sizes[0] / 64;   // 100000
    const int E = in_sizes[7];        // 1600000
    const int nb = (N + 255) / 256;   // 391 scan blocks

    // ---- workspace carve-up (all 256B-aligned) ----
    char* p = (char*)d_ws;
    auto carve = [&](size_t bytes) {
        char* r = p;
        p += (bytes + 255) & ~(size_t)255;
        return r;
    };
    float* A      = (float*)carve((size_t)N * 64 * sizeof(float));
    float* B      = (float*)carve((size_t)N * 64 * sizeof(float));
    float* s3b    = (float*)carve((size_t)N * sizeof(float));
    float* w3s    = (float*)carve(65 * sizeof(float));
    int*   counts = (int*)carve((size_t)N * sizeof(int));
    int*   exc    = (int*)carve((size_t)N * sizeof(int));
    int*   bsums  = (int*)carve(512 * sizeof(int));
    int*   rowptr = (int*)carve((size_t)(N + 1) * sizeof(int));
    int*   cursor = (int*)carve((size_t)N * sizeof(int));
    int*   esrc   = (int*)carve((size_t)E * sizeof(int));
    float* out    = (float*)d_out;

    const int eb = (E + 255) / 256;              // 6250 edge blocks
    const int gemm_blocks = N / 16;              // 6250
    const int agg_blocks  = (N * 16 + 255) / 256;

    // ---- CSR build (overlaps nothing; depends only on dst/src) ----
    hipMemsetAsync(counts, 0, (size_t)N * sizeof(int), stream);
    hipMemsetAsync(cursor, 0, (size_t)N * sizeof(int), stream);
    hist_kernel <<<eb, 256, 0, stream>>>(dst, counts, E);
    scan1_kernel<<<nb, 256, 0, stream>>>(counts, exc, bsums, N);
    scan2_kernel<<<1, 512, 0, stream>>>(bsums, nb);
    scan3_kernel<<<nb, 256, 0, stream>>>(exc, bsums, rowptr, N, E);
    build_kernel<<<eb, 256, 0, stream>>>(src, dst, rowptr, cursor, esrc, E);

    // ---- Layer 1 ----
    gemm_kernel<false><<<gemm_blocks, 256, 0, stream>>>(x, W1, b1, A);
    gather_agg_kernel<<<agg_blocks, 256, 0, stream>>>(A, esrc, rowptr, B, N);

    // ---- Layer 2 (tanh fused into GEMM input load) ----
    gemm_kernel<true><<<gemm_blocks, 256, 0, stream>>>(B, W2, b2, A);
    gather_agg_kernel<<<agg_blocks, 256, 0, stream>>>(A, esrc, rowptr, B, N);

    // ---- Layer 3 collapsed: s3 = tanh(agg2) . colsum(W3) + sum(b3) ----
    w3s_kernel<<<1, 64, 0, stream>>>(W3, b3, w3s);
    s3_kernel<<<(N + 63) / 64, 256, 0, stream>>>(B, w3s, s3b, N);
    hipMemsetAsync(out, 0, NGRAPHS * sizeof(float), stream);
    graph_reduce_kernel<<<nb, 256, 0, stream>>>(s3b, esrc, rowptr, n2g, out, N);
}

// Round 3
// 345.452 us; speedup vs baseline: 8.6805x; 1.5400x over previous
//
#include <hip/hip_runtime.h>
#include <math.h>

#define NGRAPHS 8
#define KBSHIFT 9            // bucket = dst >> 9  (512 nodes per bucket)
#define BSZ 512              // nodes per bucket

// ---------------------------------------------------------------------------
// GEMM: out[n][o] = sum_i f(in[n][i]) * W[o][i] + b[o]   (f = tanh if TANH)
// Wt padded to 68 floats/row -> i*68 + o4*4 is 16B-aligned => ds_read_b128,
// and the 16 distinct 16B chunks per wave span all 32 banks (conflict-free).
// ---------------------------------------------------------------------------
template<bool TANH>
__global__ __launch_bounds__(256) void gemm_kernel(
    const float* __restrict__ in, const float* __restrict__ W,
    const float* __restrict__ bias, float* __restrict__ out)
{
    __shared__ float Wt[64 * 68];   // Wt[i*68 + o] = W[o][i]
    __shared__ float xs[16 * 65];   // xs[nl*65 + i]
    const int t = threadIdx.x;
    const int node0 = blockIdx.x * 16;

    #pragma unroll
    for (int k = 0; k < 16; ++k) {
        int idx = k * 256 + t;
        int o = idx >> 6, i = idx & 63;
        Wt[i * 68 + o] = W[idx];
    }
    #pragma unroll
    for (int k = 0; k < 4; ++k) {
        int idx = k * 256 + t;
        int nl = idx >> 6, i = idx & 63;
        float v = in[node0 * 64 + idx];
        if (TANH) v = tanhf(v);
        xs[nl * 65 + i] = v;
    }
    __syncthreads();

    const int nl = t >> 4;
    const int o4 = t & 15;
    float4 acc = make_float4(0.f, 0.f, 0.f, 0.f);
    #pragma unroll
    for (int i = 0; i < 64; ++i) {
        float xv = xs[nl * 65 + i];
        float4 wv = *(const float4*)&Wt[i * 68 + o4 * 4];
        acc.x += xv * wv.x;
        acc.y += xv * wv.y;
        acc.z += xv * wv.z;
        acc.w += xv * wv.w;
    }
    float4 b4 = ((const float4*)bias)[o4];
    acc.x += b4.x; acc.y += b4.y; acc.z += b4.z; acc.w += b4.w;
    ((float4*)out)[(node0 + nl) * 16 + o4] = acc;
}

// ---------------------------------------------------------------------------
// Bucket histogram: bcnt[k] = #edges with dst>>9 == k.  LDS hist per block,
// one global atomic per bucket per block.
// ---------------------------------------------------------------------------
__global__ __launch_bounds__(256) void bhist_kernel(
    const int* __restrict__ dst, int* __restrict__ bcnt, int E, int K)
{
    __shared__ int h[256];
    int t = threadIdx.x;
    h[t] = 0;
    __syncthreads();
    for (int e = blockIdx.x * 256 + t; e < E; e += gridDim.x * 256)
        atomicAdd(&h[dst[e] >> KBSHIFT], 1);
    __syncthreads();
    if (t < K && h[t] > 0) atomicAdd(&bcnt[t], h[t]);
}

// ---------------------------------------------------------------------------
// Single-block exclusive scan of K (<=256) bucket counts -> bbase[0..K],
// init bcursor = bbase, set rowptr[N] = E.
// ---------------------------------------------------------------------------
__global__ __launch_bounds__(256) void bscan_kernel(
    const int* __restrict__ bcnt, int* __restrict__ bbase,
    int* __restrict__ bcursor, int* __restrict__ rowptr, int K, int N, int E)
{
    __shared__ int tmp[256];
    int t = threadIdx.x;
    int v = (t < K) ? bcnt[t] : 0;
    tmp[t] = v;
    __syncthreads();
    #pragma unroll
    for (int off = 1; off < 256; off <<= 1) {
        int u = (t >= off) ? tmp[t - off] : 0;
        __syncthreads();
        tmp[t] += u;
        __syncthreads();
    }
    int excl = tmp[t] - v;
    if (t < K) { bbase[t] = excl; bcursor[t] = excl; }
    if (t == 0) { bbase[K] = E; rowptr[N] = E; }
}

// ---------------------------------------------------------------------------
// Partition edges into buckets. Per block: (A) LDS hist of its edge range,
// (B) one global reservation per bucket, (C) scatter (dst,src) pairs into
// a DENSE per-block sub-range of each bucket (~32 pairs = 256B contiguous).
// ---------------------------------------------------------------------------
__global__ __launch_bounds__(256) void partition_kernel(
    const int* __restrict__ src, const int* __restrict__ dst,
    int* __restrict__ bcursor, int2* __restrict__ pairs, int E, int K, int chunk)
{
    __shared__ int h[256];
    __shared__ int base[256];
    __shared__ int c[256];
    int t = threadIdx.x;
    int lo = blockIdx.x * chunk;
    int hi = lo + chunk; if (hi > E) hi = E;

    h[t] = 0; c[t] = 0;
    __syncthreads();
    for (int e = lo + t; e < hi; e += 256)
        atomicAdd(&h[dst[e] >> KBSHIFT], 1);
    __syncthreads();
    if (t < K) base[t] = (h[t] > 0) ? atomicAdd(&bcursor[t], h[t]) : 0;
    __syncthreads();
    for (int e = lo + t; e < hi; e += 256) {
        int d = dst[e];
        int k = d >> KBSHIFT;
        int pos = atomicAdd(&c[k], 1);
        pairs[base[k] + pos] = make_int2(d, src[e]);
    }
}

// ---------------------------------------------------------------------------
// Per-bucket CSR finalize: one block per bucket. LDS node-hist (512) ->
// LDS exclusive scan -> rowptr write -> esrc scatter into the bucket's
// contiguous ~32KB window (every line written by THIS block only).
// ---------------------------------------------------------------------------
__global__ __launch_bounds__(512) void bucket_build_kernel(
    const int2* __restrict__ pairs, const int* __restrict__ bbase,
    int* __restrict__ rowptr, int* __restrict__ esrc, int N)
{
    __shared__ int cnt[BSZ];
    __shared__ int tmp[BSZ];
    __shared__ int cur[BSZ];
    int k = blockIdx.x;
    int t = threadIdx.x;
    int ebase = bbase[k], eend = bbase[k + 1];

    cnt[t] = 0;
    __syncthreads();
    for (int e = ebase + t; e < eend; e += BSZ)
        atomicAdd(&cnt[pairs[e].x & (BSZ - 1)], 1);
    __syncthreads();

    int v = cnt[t];
    tmp[t] = v;
    __syncthreads();
    #pragma unroll
    for (int off = 1; off < BSZ; off <<= 1) {
        int u = (t >= off) ? tmp[t - off] : 0;
        __syncthreads();
        tmp[t] += u;
        __syncthreads();
    }
    int excl = tmp[t] - v;
    cur[t] = excl;
    int n = (k << KBSHIFT) + t;
    if (n < N) rowptr[n] = ebase + excl;
    __syncthreads();

    for (int e = ebase + t; e < eend; e += BSZ) {
        int2 p = pairs[e];
        int pos = atomicAdd(&cur[p.x & (BSZ - 1)], 1);
        esrc[ebase + pos] = p.y;
    }
}

// ---------------------------------------------------------------------------
// Gather-aggregate: one WAVE per node, 4 edges in flight (sub = lane>>4),
// float4 per 16-lane group -> each row read is a coalesced 256B segment.
// ---------------------------------------------------------------------------
__global__ __launch_bounds__(256) void gather_agg_kernel(
    const float* __restrict__ m, const int* __restrict__ esrc,
    const int* __restrict__ rowptr, float* __restrict__ out, int N)
{
    int n = blockIdx.x * 4 + (threadIdx.x >> 6);
    if (n >= N) return;
    int lane = threadIdx.x & 63;
    int sub = lane >> 4, c = lane & 15;
    int beg = rowptr[n], end = rowptr[n + 1];
    float4 acc = make_float4(0.f, 0.f, 0.f, 0.f);
    for (int e = beg + sub; e < end; e += 4) {
        int s = esrc[e];
        float4 v = ((const float4*)m)[(size_t)s * 16 + c];
        acc.x += v.x; acc.y += v.y; acc.z += v.z; acc.w += v.w;
    }
    acc.x += __shfl_xor(acc.x, 16); acc.y += __shfl_xor(acc.y, 16);
    acc.z += __shfl_xor(acc.z, 16); acc.w += __shfl_xor(acc.w, 16);
    acc.x += __shfl_xor(acc.x, 32); acc.y += __shfl_xor(acc.y, 32);
    acc.z += __shfl_xor(acc.z, 32); acc.w += __shfl_xor(acc.w, 32);
    if (sub == 0) ((float4*)out)[(size_t)n * 16 + c] = acc;
}

// ---------------------------------------------------------------------------
// Gather-aggregate fused with collapsed layer 3:
// s3[n] = tanh(sum_row m) . w3s + w3s[64]    (one wave per node)
// ---------------------------------------------------------------------------
__global__ __launch_bounds__(256) void gather_s3_kernel(
    const float* __restrict__ m, const int* __restrict__ esrc,
    const int* __restrict__ rowptr, const float* __restrict__ w3s,
    float* __restrict__ s3, int N)
{
    int n = blockIdx.x * 4 + (threadIdx.x >> 6);
    if (n >= N) return;
    int lane = threadIdx.x & 63;
    int sub = lane >> 4, c = lane & 15;
    int beg = rowptr[n], end = rowptr[n + 1];
    float4 acc = make_float4(0.f, 0.f, 0.f, 0.f);
    for (int e = beg + sub; e < end; e += 4) {
        int s = esrc[e];
        float4 v = ((const float4*)m)[(size_t)s * 16 + c];
        acc.x += v.x; acc.y += v.y; acc.z += v.z; acc.w += v.w;
    }
    acc.x += __shfl_xor(acc.x, 16); acc.y += __shfl_xor(acc.y, 16);
    acc.z += __shfl_xor(acc.z, 16); acc.w += __shfl_xor(acc.w, 16);
    acc.x += __shfl_xor(acc.x, 32); acc.y += __shfl_xor(acc.y, 32);
    acc.z += __shfl_xor(acc.z, 32); acc.w += __shfl_xor(acc.w, 32);
    float4 w = ((const float4*)w3s)[c];
    float partial = tanhf(acc.x) * w.x + tanhf(acc.y) * w.y
                  + tanhf(acc.z) * w.z + tanhf(acc.w) * w.w;
    partial += __shfl_xor(partial, 1);
    partial += __shfl_xor(partial, 2);
    partial += __shfl_xor(partial, 4);
    partial += __shfl_xor(partial, 8);
    if (lane == 0) s3[n] = partial + w3s[64];
}

// ---------------------------------------------------------------------------
// w3s[i] = sum_o W3[o][i];  w3s[64] = sum(b3)
// ---------------------------------------------------------------------------
__global__ void w3s_kernel(const float* __restrict__ W3,
                           const float* __restrict__ b3,
                           float* __restrict__ w3s)
{
    int i = threadIdx.x;   // 64 threads
    float s = 0.f;
    for (int o = 0; o < 64; ++o) s += W3[o * 64 + i];
    w3s[i] = s;
    if (i == 0) {
        float bs = 0.f;
        for (int k = 0; k < 64; ++k) bs += b3[k];
        w3s[64] = bs;
    }
}

// ---------------------------------------------------------------------------
// per_graph[n2g[n]] += sum_{e in in(n)} s3[esrc[e]]   via CSR, LDS bins.
// ---------------------------------------------------------------------------
__global__ __launch_bounds__(256) void graph_reduce_kernel(
    const float* __restrict__ s3, const int* __restrict__ esrc,
    const int* __restrict__ rowptr, const int* __restrict__ n2g,
    float* __restrict__ out, int N)
{
    __shared__ float bins[NGRAPHS];
    int t = threadIdx.x;
    if (t < NGRAPHS) bins[t] = 0.f;
    __syncthreads();
    int n = blockIdx.x * 256 + t;
    if (n < N) {
        float acc = 0.f;
        for (int e = rowptr[n]; e < rowptr[n + 1]; ++e) acc += s3[esrc[e]];
        atomicAdd(&bins[n2g[n]], acc);
    }
    __syncthreads();
    if (t < NGRAPHS) unsafeAtomicAdd(&out[t], bins[t]);
}

// ---------------------------------------------------------------------------
extern "C" void kernel_launch(void* const* d_in, const int* in_sizes, int n_in,
                              void* d_out, int out_size, void* d_ws, size_t ws_size,
                              hipStream_t stream)
{
    const float* x   = (const float*)d_in[0];
    const float* W1  = (const float*)d_in[1];
    const float* b1  = (const float*)d_in[2];
    const float* W2  = (const float*)d_in[3];
    const float* b2  = (const float*)d_in[4];
    const float* W3  = (const float*)d_in[5];
    const float* b3  = (const float*)d_in[6];
    const int*   src = (const int*)d_in[7];
    const int*   dst = (const int*)d_in[8];
    const int*   n2g = (const int*)d_in[9];

    const int N = in_sizes[0] / 64;   // 100000
    const int E = in_sizes[7];        // 1600000
    const int K = (N + BSZ - 1) >> KBSHIFT;   // 196 buckets (<=256 for N<=128k)
    const int nb = (N + 255) / 256;

    // ---- workspace carve-up (256B-aligned) ----
    char* p = (char*)d_ws;
    auto carve = [&](size_t bytes) {
        char* r = p;
        p += (bytes + 255) & ~(size_t)255;
        return r;
    };
    float* A      = (float*)carve((size_t)N * 64 * sizeof(float));
    float* B      = (float*)carve((size_t)N * 64 * sizeof(float));
    float* s3b    = (float*)carve((size_t)N * sizeof(float));
    float* w3s    = (float*)carve(65 * sizeof(float));
    int*   bcnt   = (int*)carve(256 * sizeof(int));
    int*   bbase  = (int*)carve(257 * sizeof(int));
    int*   bcursor= (int*)carve(256 * sizeof(int));
    int*   rowptr = (int*)carve((size_t)(N + 1) * sizeof(int));
    int*   esrc   = (int*)carve((size_t)E * sizeof(int));
    // pairs (E * int2 = 12.8MB) aliases B: dead before gather_agg writes B.
    int2*  pairs  = (int2*)B;
    float* out    = (float*)d_out;

    const int gemm_blocks = N / 16;
    const int gath_blocks = (N + 3) / 4;
    const int chunk = (E + 255) / 256;   // partition: 256 blocks, fixed ranges

    // ---- CSR build: two-level counting sort ----
    hipMemsetAsync(bcnt, 0, 256 * sizeof(int), stream);
    bhist_kernel   <<<256, 256, 0, stream>>>(dst, bcnt, E, K);
    bscan_kernel   <<<1, 256, 0, stream>>>(bcnt, bbase, bcursor, rowptr, K, N, E);
    partition_kernel<<<256, 256, 0, stream>>>(src, dst, bcursor, pairs, E, K, chunk);
    bucket_build_kernel<<<K, BSZ, 0, stream>>>(pairs, bbase, rowptr, esrc, N);

    // ---- Layer 1 ----
    gemm_kernel<false><<<gemm_blocks, 256, 0, stream>>>(x, W1, b1, A);
    gather_agg_kernel<<<gath_blocks, 256, 0, stream>>>(A, esrc, rowptr, B, N);

    // ---- Layer 2 (tanh fused into GEMM input load) ----
    gemm_kernel<true><<<gemm_blocks, 256, 0, stream>>>(B, W2, b2, A);

    // ---- Layer 3 collapsed + fused into gather 2 ----
    w3s_kernel<<<1, 64, 0, stream>>>(W3, b3, w3s);
    gather_s3_kernel<<<gath_blocks, 256, 0, stream>>>(A, esrc, rowptr, w3s, s3b, N);

    hipMemsetAsync(out, 0, NGRAPHS * sizeof(float), stream);
    graph_reduce_kernel<<<nb, 256, 0, stream>>>(s3b, esrc, rowptr, n2g, out, N);
}

// Round 4
// 318.610 us; speedup vs baseline: 9.4118x; 1.0842x over previous
//
#include <hip/hip_runtime.h>
#include <math.h>

#define NGRAPHS 8
#define KBSHIFT 9            // bucket = dst >> 9  (512 nodes per bucket)
#define BSZ 512              // nodes per bucket
// NOTE: partition packs (dst&511)<<23 | src -> requires src < 2^23 (N=100k ok)

// ---- bf16 helpers (RNE pack; values are tanh-bounded, no NaN handling) ----
__device__ __forceinline__ float bfl(unsigned u) { return __uint_as_float(u << 16); }
__device__ __forceinline__ float bfh(unsigned u) { return __uint_as_float(u & 0xffff0000u); }
__device__ __forceinline__ unsigned f2bf1(float f) {
    unsigned u = __float_as_uint(f);
    return (u + 0x7fffu + ((u >> 16) & 1u)) >> 16;
}
__device__ __forceinline__ unsigned p2bf(float a, float b) {
    return f2bf1(a) | (f2bf1(b) << 16);
}

// ---------------------------------------------------------------------------
// GEMM: out[n][o] = sum_i f(in[n][i]) * W[o][i] + b[o]   (f = tanh if TANH)
// INBF: input rows are bf16 (64 ch = 32 uints). Output always bf16.
// Wt padded to 68 -> float4 LDS reads are 16B-aligned, 2-way alias only.
// ---------------------------------------------------------------------------
template<bool TANH, bool INBF>
__global__ __launch_bounds__(256) void gemm_kernel(
    const void* __restrict__ in_, const float* __restrict__ W,
    const float* __restrict__ bias, unsigned* __restrict__ out)
{
    __shared__ float Wt[64 * 68];   // Wt[i*68 + o] = W[o][i]
    __shared__ float xs[16 * 65];   // xs[nl*65 + i]
    const int t = threadIdx.x;
    const int node0 = blockIdx.x * 16;

    #pragma unroll
    for (int k = 0; k < 16; ++k) {
        int idx = k * 256 + t;
        int o = idx >> 6, i = idx & 63;
        Wt[i * 68 + o] = W[idx];
    }
    if (INBF) {
        const unsigned* in = (const unsigned*)in_;   // 2 bf16 per uint
        #pragma unroll
        for (int k = 0; k < 2; ++k) {
            int idx = k * 256 + t;                   // 512 uints = 1024 ch
            int nl = idx >> 5, ii = (idx & 31) * 2;
            unsigned u = in[node0 * 32 + idx];
            float a = bfl(u), b = bfh(u);
            if (TANH) { a = tanhf(a); b = tanhf(b); }
            xs[nl * 65 + ii] = a;
            xs[nl * 65 + ii + 1] = b;
        }
    } else {
        const float* in = (const float*)in_;
        #pragma unroll
        for (int k = 0; k < 4; ++k) {
            int idx = k * 256 + t;
            int nl = idx >> 6, i = idx & 63;
            float v = in[node0 * 64 + idx];
            if (TANH) v = tanhf(v);
            xs[nl * 65 + i] = v;
        }
    }
    __syncthreads();

    const int nl = t >> 4;
    const int o4 = t & 15;
    float4 acc = make_float4(0.f, 0.f, 0.f, 0.f);
    #pragma unroll
    for (int i = 0; i < 64; ++i) {
        float xv = xs[nl * 65 + i];
        float4 wv = *(const float4*)&Wt[i * 68 + o4 * 4];
        acc.x += xv * wv.x;
        acc.y += xv * wv.y;
        acc.z += xv * wv.z;
        acc.w += xv * wv.w;
    }
    float4 b4 = ((const float4*)bias)[o4];
    acc.x += b4.x; acc.y += b4.y; acc.z += b4.z; acc.w += b4.w;
    uint2 o;
    o.x = p2bf(acc.x, acc.y);
    o.y = p2bf(acc.z, acc.w);
    ((uint2*)out)[(node0 + nl) * 16 + o4] = o;   // row = 128B, o4*8B offset
}

// ---------------------------------------------------------------------------
// Bucket histogram: bcnt[k] = #edges with dst>>9 == k.
// ---------------------------------------------------------------------------
__global__ __launch_bounds__(256) void bhist_kernel(
    const int* __restrict__ dst, int* __restrict__ bcnt, int E, int K)
{
    __shared__ int h[256];
    int t = threadIdx.x;
    h[t] = 0;
    __syncthreads();
    for (int e = blockIdx.x * 256 + t; e < E; e += gridDim.x * 256)
        atomicAdd(&h[dst[e] >> KBSHIFT], 1);
    __syncthreads();
    if (t < K && h[t] > 0) atomicAdd(&bcnt[t], h[t]);
}

// ---------------------------------------------------------------------------
// Exclusive scan of K (<=256) bucket counts -> bbase[0..K], bcursor=bbase.
// ---------------------------------------------------------------------------
__global__ __launch_bounds__(256) void bscan_kernel(
    const int* __restrict__ bcnt, int* __restrict__ bbase,
    int* __restrict__ bcursor, int* __restrict__ rowptr, int K, int N, int E)
{
    __shared__ int tmp[256];
    int t = threadIdx.x;
    int v = (t < K) ? bcnt[t] : 0;
    tmp[t] = v;
    __syncthreads();
    #pragma unroll
    for (int off = 1; off < 256; off <<= 1) {
        int u = (t >= off) ? tmp[t - off] : 0;
        __syncthreads();
        tmp[t] += u;
        __syncthreads();
    }
    int excl = tmp[t] - v;
    if (t < K) { bbase[t] = excl; bcursor[t] = excl; }
    if (t == 0) { bbase[K] = E; rowptr[N] = E; }
}

// ---------------------------------------------------------------------------
// Partition edges into buckets; packed pair = (dst&511)<<23 | src.
// ---------------------------------------------------------------------------
__global__ __launch_bounds__(256) void partition_kernel(
    const int* __restrict__ src, const int* __restrict__ dst,
    int* __restrict__ bcursor, unsigned* __restrict__ pairs, int E, int K, int chunk)
{
    __shared__ int h[256];
    __shared__ int base[256];
    __shared__ int c[256];
    int t = threadIdx.x;
    int lo = blockIdx.x * chunk;
    int hi = lo + chunk; if (hi > E) hi = E;

    h[t] = 0; c[t] = 0;
    __syncthreads();
    for (int e = lo + t; e < hi; e += 256)
        atomicAdd(&h[dst[e] >> KBSHIFT], 1);
    __syncthreads();
    if (t < K) base[t] = (h[t] > 0) ? atomicAdd(&bcursor[t], h[t]) : 0;
    __syncthreads();
    for (int e = lo + t; e < hi; e += 256) {
        int d = dst[e];
        int k = d >> KBSHIFT;
        int pos = atomicAdd(&c[k], 1);
        pairs[base[k] + pos] = ((unsigned)(d & (BSZ - 1)) << 23) | (unsigned)src[e];
    }
}

// ---------------------------------------------------------------------------
// Per-bucket CSR finalize: LDS hist -> scan -> rowptr + esrc scatter into
// the bucket's contiguous window (every line written by one block only).
// ---------------------------------------------------------------------------
__global__ __launch_bounds__(512) void bucket_build_kernel(
    const unsigned* __restrict__ pairs, const int* __restrict__ bbase,
    int* __restrict__ rowptr, int* __restrict__ esrc, int N)
{
    __shared__ int cnt[BSZ];
    __shared__ int tmp[BSZ];
    __shared__ int cur[BSZ];
    int k = blockIdx.x;
    int t = threadIdx.x;
    int ebase = bbase[k], eend = bbase[k + 1];

    cnt[t] = 0;
    __syncthreads();
    for (int e = ebase + t; e < eend; e += BSZ)
        atomicAdd(&cnt[pairs[e] >> 23], 1);
    __syncthreads();

    int v = cnt[t];
    tmp[t] = v;
    __syncthreads();
    #pragma unroll
    for (int off = 1; off < BSZ; off <<= 1) {
        int u = (t >= off) ? tmp[t - off] : 0;
        __syncthreads();
        tmp[t] += u;
        __syncthreads();
    }
    int excl = tmp[t] - v;
    cur[t] = excl;
    int n = (k << KBSHIFT) + t;
    if (n < N) rowptr[n] = ebase + excl;
    __syncthreads();

    for (int e = ebase + t; e < eend; e += BSZ) {
        unsigned p = pairs[e];
        int pos = atomicAdd(&cur[p >> 23], 1);
        esrc[ebase + pos] = (int)(p & 0x7fffffu);
    }
}

// ---------------------------------------------------------------------------
// Gather-aggregate (bf16 rows): one wave per node, 8 edges in flight,
// 8 lanes x 16B per 128B row. fp32 accumulate, bf16 store.
// ---------------------------------------------------------------------------
__global__ __launch_bounds__(256) void gather_agg_kernel(
    const uint4* __restrict__ m, const int* __restrict__ esrc,
    const int* __restrict__ rowptr, uint4* __restrict__ out, int N)
{
    int n = blockIdx.x * 4 + (threadIdx.x >> 6);
    if (n >= N) return;
    int lane = threadIdx.x & 63;
    int sub = lane >> 3, c = lane & 7;
    int beg = rowptr[n], end = rowptr[n + 1];
    float2 a0 = {0.f, 0.f}, a1 = {0.f, 0.f}, a2 = {0.f, 0.f}, a3 = {0.f, 0.f};
    for (int e = beg + sub; e < end; e += 8) {
        int s = esrc[e];
        uint4 v = m[(size_t)s * 8 + c];
        a0.x += bfl(v.x); a0.y += bfh(v.x);
        a1.x += bfl(v.y); a1.y += bfh(v.y);
        a2.x += bfl(v.z); a2.y += bfh(v.z);
        a3.x += bfl(v.w); a3.y += bfh(v.w);
    }
    #pragma unroll
    for (int d = 8; d <= 32; d <<= 1) {
        a0.x += __shfl_xor(a0.x, d); a0.y += __shfl_xor(a0.y, d);
        a1.x += __shfl_xor(a1.x, d); a1.y += __shfl_xor(a1.y, d);
        a2.x += __shfl_xor(a2.x, d); a2.y += __shfl_xor(a2.y, d);
        a3.x += __shfl_xor(a3.x, d); a3.y += __shfl_xor(a3.y, d);
    }
    if (sub == 0) {
        uint4 o;
        o.x = p2bf(a0.x, a0.y);
        o.y = p2bf(a1.x, a1.y);
        o.z = p2bf(a2.x, a2.y);
        o.w = p2bf(a3.x, a3.y);
        out[(size_t)n * 8 + c] = o;
    }
}

// ---------------------------------------------------------------------------
// Gather + collapsed layer 3: s3[n] = tanh(sum_row m) . w3s + w3s[64]
// ---------------------------------------------------------------------------
__global__ __launch_bounds__(256) void gather_s3_kernel(
    const uint4* __restrict__ m, const int* __restrict__ esrc,
    const int* __restrict__ rowptr, const float* __restrict__ w3s,
    float* __restrict__ s3, int N)
{
    int n = blockIdx.x * 4 + (threadIdx.x >> 6);
    if (n >= N) return;
    int lane = threadIdx.x & 63;
    int sub = lane >> 3, c = lane & 7;
    int beg = rowptr[n], end = rowptr[n + 1];
    float2 a0 = {0.f, 0.f}, a1 = {0.f, 0.f}, a2 = {0.f, 0.f}, a3 = {0.f, 0.f};
    for (int e = beg + sub; e < end; e += 8) {
        int s = esrc[e];
        uint4 v = m[(size_t)s * 8 + c];
        a0.x += bfl(v.x); a0.y += bfh(v.x);
        a1.x += bfl(v.y); a1.y += bfh(v.y);
        a2.x += bfl(v.z); a2.y += bfh(v.z);
        a3.x += bfl(v.w); a3.y += bfh(v.w);
    }
    #pragma unroll
    for (int d = 8; d <= 32; d <<= 1) {
        a0.x += __shfl_xor(a0.x, d); a0.y += __shfl_xor(a0.y, d);
        a1.x += __shfl_xor(a1.x, d); a1.y += __shfl_xor(a1.y, d);
        a2.x += __shfl_xor(a2.x, d); a2.y += __shfl_xor(a2.y, d);
        a3.x += __shfl_xor(a3.x, d); a3.y += __shfl_xor(a3.y, d);
    }
    // lane c holds channels c*8..c*8+7 (full sums after xor-reduce)
    float4 w0 = ((const float4*)w3s)[c * 2];
    float4 w1 = ((const float4*)w3s)[c * 2 + 1];
    float partial = tanhf(a0.x) * w0.x + tanhf(a0.y) * w0.y
                  + tanhf(a1.x) * w0.z + tanhf(a1.y) * w0.w
                  + tanhf(a2.x) * w1.x + tanhf(a2.y) * w1.y
                  + tanhf(a3.x) * w1.z + tanhf(a3.y) * w1.w;
    partial += __shfl_xor(partial, 1);
    partial += __shfl_xor(partial, 2);
    partial += __shfl_xor(partial, 4);
    if (lane == 0) s3[n] = partial + w3s[64];
}

// ---------------------------------------------------------------------------
// w3s[i] = sum_o W3[o][i];  w3s[64] = sum(b3)
// ---------------------------------------------------------------------------
__global__ void w3s_kernel(const float* __restrict__ W3,
                           const float* __restrict__ b3,
                           float* __restrict__ w3s)
{
    int i = threadIdx.x;   // 64 threads
    float s = 0.f;
    for (int o = 0; o < 64; ++o) s += W3[o * 64 + i];
    w3s[i] = s;
    if (i == 0) {
        float bs = 0.f;
        for (int k = 0; k < 64; ++k) bs += b3[k];
        w3s[64] = bs;
    }
}

// ---------------------------------------------------------------------------
// per_graph[n2g[n]] += sum_{e in in(n)} s3[esrc[e]]   via CSR, LDS bins.
// ---------------------------------------------------------------------------
__global__ __launch_bounds__(256) void graph_reduce_kernel(
    const float* __restrict__ s3, const int* __restrict__ esrc,
    const int* __restrict__ rowptr, const int* __restrict__ n2g,
    float* __restrict__ out, int N)
{
    __shared__ float bins[NGRAPHS];
    int t = threadIdx.x;
    if (t < NGRAPHS) bins[t] = 0.f;
    __syncthreads();
    int n = blockIdx.x * 256 + t;
    if (n < N) {
        float acc = 0.f;
        for (int e = rowptr[n]; e < rowptr[n + 1]; ++e) acc += s3[esrc[e]];
        atomicAdd(&bins[n2g[n]], acc);
    }
    __syncthreads();
    if (t < NGRAPHS) unsafeAtomicAdd(&out[t], bins[t]);
}

// ---------------------------------------------------------------------------
extern "C" void kernel_launch(void* const* d_in, const int* in_sizes, int n_in,
                              void* d_out, int out_size, void* d_ws, size_t ws_size,
                              hipStream_t stream)
{
    const float* x   = (const float*)d_in[0];
    const float* W1  = (const float*)d_in[1];
    const float* b1  = (const float*)d_in[2];
    const float* W2  = (const float*)d_in[3];
    const float* b2  = (const float*)d_in[4];
    const float* W3  = (const float*)d_in[5];
    const float* b3  = (const float*)d_in[6];
    const int*   src = (const int*)d_in[7];
    const int*   dst = (const int*)d_in[8];
    const int*   n2g = (const int*)d_in[9];

    const int N = in_sizes[0] / 64;   // 100000
    const int E = in_sizes[7];        // 1600000
    const int K = (N + BSZ - 1) >> KBSHIFT;   // 196 buckets
    const int nb = (N + 255) / 256;

    // ---- workspace carve-up (256B-aligned) ----
    char* p = (char*)d_ws;
    auto carve = [&](size_t bytes) {
        char* r = p;
        p += (bytes + 255) & ~(size_t)255;
        return r;
    };
    unsigned* A     = (unsigned*)carve((size_t)N * 64 * 2);  // bf16 rows (12.8MB)
    unsigned* B     = (unsigned*)carve((size_t)N * 64 * 2);  // bf16 rows (12.8MB)
    float* s3b      = (float*)carve((size_t)N * sizeof(float));
    float* w3s      = (float*)carve(65 * sizeof(float));
    int*   bcnt     = (int*)carve(256 * sizeof(int));
    int*   bbase    = (int*)carve(257 * sizeof(int));
    int*   bcursor  = (int*)carve(256 * sizeof(int));
    int*   rowptr   = (int*)carve((size_t)(N + 1) * sizeof(int));
    int*   esrc     = (int*)carve((size_t)E * sizeof(int));
    // packed pairs (E*4B = 6.4MB) alias B: dead before gather_agg writes B.
    unsigned* pairs = (unsigned*)B;
    float* out      = (float*)d_out;

    const int gemm_blocks = N / 16;
    const int gath_blocks = (N + 3) / 4;
    const int chunk = (E + 255) / 256;

    // ---- CSR build: two-level counting sort ----
    hipMemsetAsync(bcnt, 0, 256 * sizeof(int), stream);
    bhist_kernel   <<<256, 256, 0, stream>>>(dst, bcnt, E, K);
    bscan_kernel   <<<1, 256, 0, stream>>>(bcnt, bbase, bcursor, rowptr, K, N, E);
    partition_kernel<<<256, 256, 0, stream>>>(src, dst, bcursor, pairs, E, K, chunk);
    bucket_build_kernel<<<K, BSZ, 0, stream>>>(pairs, bbase, rowptr, esrc, N);

    // ---- Layer 1: x (fp32) -> A (bf16) ----
    gemm_kernel<false, false><<<gemm_blocks, 256, 0, stream>>>(x, W1, b1, A);
    gather_agg_kernel<<<gath_blocks, 256, 0, stream>>>((const uint4*)A, esrc, rowptr, (uint4*)B, N);

    // ---- Layer 2: tanh fused into bf16 input load ----
    gemm_kernel<true, true><<<gemm_blocks, 256, 0, stream>>>(B, W2, b2, A);

    // ---- Layer 3 collapsed + fused into gather 2 ----
    w3s_kernel<<<1, 64, 0, stream>>>(W3, b3, w3s);
    gather_s3_kernel<<<gath_blocks, 256, 0, stream>>>((const uint4*)A, esrc, rowptr, w3s, s3b, N);

    hipMemsetAsync(out, 0, NGRAPHS * sizeof(float), stream);
    graph_reduce_kernel<<<nb, 256, 0, stream>>>(s3b, esrc, rowptr, n2g, out, N);
}

// Round 6
// 297.820 us; speedup vs baseline: 10.0689x; 1.0698x over previous
//
#include <hip/hip_runtime.h>
#include <math.h>

#define NGRAPHS 8
#define KBSHIFT 9            // bucket = dst >> 9  (512 nodes per bucket)
#define BSZ 512              // nodes per bucket
// NOTE: partition packs (dst&511)<<23 | src -> requires src < 2^23 (N=100k ok)

typedef _Float16 h2 __attribute__((ext_vector_type(2)));

__device__ __forceinline__ h2 as_h2(unsigned u) { return __builtin_bit_cast(h2, u); }
__device__ __forceinline__ unsigned pkf16(float a, float b) {
    auto v = __builtin_amdgcn_cvt_pkrtz(a, b);   // v_cvt_pkrtz_f16_f32
    return __builtin_bit_cast(unsigned, v);
}
// fast tanh: 1 - 2/(e^{2x}+1); exact at +-inf ends, ~1e-6 rel err (5 VALU)
__device__ __forceinline__ float ftanh(float x) {
    float t = __expf(2.0f * x);                       // v_exp_f32 path
    return 1.0f - 2.0f * __builtin_amdgcn_rcpf(t + 1.0f);
}
// accumulate two edges' packed-fp16 channel pair into fp32 accumulators:
// t0 = (A.lo, B.lo), t1 = (A.hi, B.hi) via v_perm; v_dot2_f32_f16 with (1,1)
__device__ __forceinline__ void acc2(float& lo, float& hi, unsigned uA, unsigned uB) {
    const h2 ONES = {(_Float16)1.0f, (_Float16)1.0f};
    unsigned t0 = __builtin_amdgcn_perm(uB, uA, 0x05040100u);
    unsigned t1 = __builtin_amdgcn_perm(uB, uA, 0x07060302u);
    lo = __builtin_amdgcn_fdot2(as_h2(t0), ONES, lo, false);
    hi = __builtin_amdgcn_fdot2(as_h2(t1), ONES, hi, false);
}
__device__ __forceinline__ void acc1(float& lo, float& hi, unsigned u) {
    h2 hv = as_h2(u);
    lo += (float)hv.x;
    hi += (float)hv.y;
}

// ---------------------------------------------------------------------------
// GEMM: out[n][o] = sum_i f(in[n][i]) * W[o][i] + b[o]   (f = ftanh if TANH)
// INH: input rows are fp16 (64 ch = 32 uints). Output always fp16.
// Wt padded to 68 -> float4 LDS reads are 16B-aligned.
// ---------------------------------------------------------------------------
template<bool TANH, bool INH>
__global__ __launch_bounds__(256) void gemm_kernel(
    const void* __restrict__ in_, const float* __restrict__ W,
    const float* __restrict__ bias, unsigned* __restrict__ out)
{
    __shared__ float Wt[64 * 68];   // Wt[i*68 + o] = W[o][i]
    __shared__ float xs[16 * 65];   // xs[nl*65 + i]
    const int t = threadIdx.x;
    const int node0 = blockIdx.x * 16;

    #pragma unroll
    for (int k = 0; k < 16; ++k) {
        int idx = k * 256 + t;
        int o = idx >> 6, i = idx & 63;
        Wt[i * 68 + o] = W[idx];
    }
    if (INH) {
        const unsigned* in = (const unsigned*)in_;   // 2 fp16 per uint
        #pragma unroll
        for (int k = 0; k < 2; ++k) {
            int idx = k * 256 + t;                   // 512 uints
            int nl = idx >> 5, ii = (idx & 31) * 2;
            h2 hv = as_h2(in[node0 * 32 + idx]);
            float a = (float)hv.x, b = (float)hv.y;
            if (TANH) { a = ftanh(a); b = ftanh(b); }
            xs[nl * 65 + ii] = a;
            xs[nl * 65 + ii + 1] = b;
        }
    } else {
        const float* in = (const float*)in_;
        #pragma unroll
        for (int k = 0; k < 4; ++k) {
            int idx = k * 256 + t;
            int nl = idx >> 6, i = idx & 63;
            float v = in[node0 * 64 + idx];
            if (TANH) v = ftanh(v);
            xs[nl * 65 + i] = v;
        }
    }
    __syncthreads();

    const int nl = t >> 4;
    const int o4 = t & 15;
    float4 acc = make_float4(0.f, 0.f, 0.f, 0.f);
    #pragma unroll
    for (int i = 0; i < 64; ++i) {
        float xv = xs[nl * 65 + i];
        float4 wv = *(const float4*)&Wt[i * 68 + o4 * 4];
        acc.x += xv * wv.x;
        acc.y += xv * wv.y;
        acc.z += xv * wv.z;
        acc.w += xv * wv.w;
    }
    float4 b4 = ((const float4*)bias)[o4];
    acc.x += b4.x; acc.y += b4.y; acc.z += b4.z; acc.w += b4.w;
    uint2 o;
    o.x = pkf16(acc.x, acc.y);
    o.y = pkf16(acc.z, acc.w);
    ((uint2*)out)[(node0 + nl) * 16 + o4] = o;   // fp16 row = 128B
}

// ---------------------------------------------------------------------------
// Bucket histogram: bcnt[k] = #edges with dst>>9 == k.
// ---------------------------------------------------------------------------
__global__ __launch_bounds__(256) void bhist_kernel(
    const int* __restrict__ dst, int* __restrict__ bcnt, int E, int K)
{
    __shared__ int h[256];
    int t = threadIdx.x;
    h[t] = 0;
    __syncthreads();
    for (int e = blockIdx.x * 256 + t; e < E; e += gridDim.x * 256)
        atomicAdd(&h[dst[e] >> KBSHIFT], 1);
    __syncthreads();
    if (t < K && h[t] > 0) atomicAdd(&bcnt[t], h[t]);
}

// ---------------------------------------------------------------------------
// Exclusive scan of K (<=256) bucket counts -> bbase[0..K], bcursor=bbase.
// ---------------------------------------------------------------------------
__global__ __launch_bounds__(256) void bscan_kernel(
    const int* __restrict__ bcnt, int* __restrict__ bbase,
    int* __restrict__ bcursor, int* __restrict__ rowptr, int K, int N, int E)
{
    __shared__ int tmp[256];
    int t = threadIdx.x;
    int v = (t < K) ? bcnt[t] : 0;
    tmp[t] = v;
    __syncthreads();
    #pragma unroll
    for (int off = 1; off < 256; off <<= 1) {
        int u = (t >= off) ? tmp[t - off] : 0;
        __syncthreads();
        tmp[t] += u;
        __syncthreads();
    }
    int excl = tmp[t] - v;
    if (t < K) { bbase[t] = excl; bcursor[t] = excl; }
    if (t == 0) { bbase[K] = E; rowptr[N] = E; }
}

// ---------------------------------------------------------------------------
// Partition edges into buckets; packed pair = (dst&511)<<23 | src.
// ---------------------------------------------------------------------------
__global__ __launch_bounds__(256) void partition_kernel(
    const int* __restrict__ src, const int* __restrict__ dst,
    int* __restrict__ bcursor, unsigned* __restrict__ pairs, int E, int K, int chunk)
{
    __shared__ int h[256];
    __shared__ int base[256];
    __shared__ int c[256];
    int t = threadIdx.x;
    int lo = blockIdx.x * chunk;
    int hi = lo + chunk; if (hi > E) hi = E;

    h[t] = 0; c[t] = 0;
    __syncthreads();
    for (int e = lo + t; e < hi; e += 256)
        atomicAdd(&h[dst[e] >> KBSHIFT], 1);
    __syncthreads();
    if (t < K) base[t] = (h[t] > 0) ? atomicAdd(&bcursor[t], h[t]) : 0;
    __syncthreads();
    for (int e = lo + t; e < hi; e += 256) {
        int d = dst[e];
        int k = d >> KBSHIFT;
        int pos = atomicAdd(&c[k], 1);
        pairs[base[k] + pos] = ((unsigned)(d & (BSZ - 1)) << 23) | (unsigned)src[e];
    }
}

// ---------------------------------------------------------------------------
// Per-bucket CSR finalize: LDS hist -> scan -> rowptr + esrc scatter into
// the bucket's contiguous window (every line written by one block only).
// ---------------------------------------------------------------------------
__global__ __launch_bounds__(512) void bucket_build_kernel(
    const unsigned* __restrict__ pairs, const int* __restrict__ bbase,
    int* __restrict__ rowptr, int* __restrict__ esrc, int N)
{
    __shared__ int cnt[BSZ];
    __shared__ int tmp[BSZ];
    __shared__ int cur[BSZ];
    int k = blockIdx.x;
    int t = threadIdx.x;
    int ebase = bbase[k], eend = bbase[k + 1];

    cnt[t] = 0;
    __syncthreads();
    for (int e = ebase + t; e < eend; e += BSZ)
        atomicAdd(&cnt[pairs[e] >> 23], 1);
    __syncthreads();

    int v = cnt[t];
    tmp[t] = v;
    __syncthreads();
    #pragma unroll
    for (int off = 1; off < BSZ; off <<= 1) {
        int u = (t >= off) ? tmp[t - off] : 0;
        __syncthreads();
        tmp[t] += u;
        __syncthreads();
    }
    int excl = tmp[t] - v;
    cur[t] = excl;
    int n = (k << KBSHIFT) + t;
    if (n < N) rowptr[n] = ebase + excl;
    __syncthreads();

    for (int e = ebase + t; e < eend; e += BSZ) {
        unsigned p = pairs[e];
        int pos = atomicAdd(&cur[p >> 23], 1);
        esrc[ebase + pos] = (int)(p & 0x7fffffu);
    }
}

// ---------------------------------------------------------------------------
// Gather-aggregate (fp16 rows): one wave per node, 16 edges in flight
// (8 subs x edge pair), perm + v_dot2_f32_f16 accumulation.
// ---------------------------------------------------------------------------
__global__ __launch_bounds__(256) void gather_agg_kernel(
    const uint4* __restrict__ m, const int* __restrict__ esrc,
    const int* __restrict__ rowptr, uint4* __restrict__ out, int N)
{
    int n = blockIdx.x * 4 + (threadIdx.x >> 6);
    if (n >= N) return;
    int lane = threadIdx.x & 63;
    int sub = lane >> 3, c = lane & 7;
    int beg = rowptr[n], end = rowptr[n + 1];
    float a[8] = {0.f, 0.f, 0.f, 0.f, 0.f, 0.f, 0.f, 0.f};
    int e = beg + sub;
    for (; e + 8 < end; e += 16) {       // edge pair (e, e+8)
        int sA = esrc[e], sB = esrc[e + 8];
        uint4 vA = m[(size_t)sA * 8 + c];
        uint4 vB = m[(size_t)sB * 8 + c];
        acc2(a[0], a[1], vA.x, vB.x);
        acc2(a[2], a[3], vA.y, vB.y);
        acc2(a[4], a[5], vA.z, vB.z);
        acc2(a[6], a[7], vA.w, vB.w);
    }
    if (e < end) {                        // tail: single edge
        uint4 vA = m[(size_t)esrc[e] * 8 + c];
        acc1(a[0], a[1], vA.x);
        acc1(a[2], a[3], vA.y);
        acc1(a[4], a[5], vA.z);
        acc1(a[6], a[7], vA.w);
    }
    #pragma unroll
    for (int d = 8; d <= 32; d <<= 1) {
        #pragma unroll
        for (int k = 0; k < 8; ++k) a[k] += __shfl_xor(a[k], d);
    }
    if (sub == 0) {
        uint4 o;
        o.x = pkf16(a[0], a[1]);
        o.y = pkf16(a[2], a[3]);
        o.z = pkf16(a[4], a[5]);
        o.w = pkf16(a[6], a[7]);
        out[(size_t)n * 8 + c] = o;
    }
}

// ---------------------------------------------------------------------------
// Gather + collapsed layer 3: s3[n] = ftanh(sum_row m) . w3s + w3s[64]
// ---------------------------------------------------------------------------
__global__ __launch_bounds__(256) void gather_s3_kernel(
    const uint4* __restrict__ m, const int* __restrict__ esrc,
    const int* __restrict__ rowptr, const float* __restrict__ w3s,
    float* __restrict__ s3, int N)
{
    int n = blockIdx.x * 4 + (threadIdx.x >> 6);
    if (n >= N) return;
    int lane = threadIdx.x & 63;
    int sub = lane >> 3, c = lane & 7;
    int beg = rowptr[n], end = rowptr[n + 1];
    float a[8] = {0.f, 0.f, 0.f, 0.f, 0.f, 0.f, 0.f, 0.f};
    int e = beg + sub;
    for (; e + 8 < end; e += 16) {
        int sA = esrc[e], sB = esrc[e + 8];
        uint4 vA = m[(size_t)sA * 8 + c];
        uint4 vB = m[(size_t)sB * 8 + c];
        acc2(a[0], a[1], vA.x, vB.x);
        acc2(a[2], a[3], vA.y, vB.y);
        acc2(a[4], a[5], vA.z, vB.z);
        acc2(a[6], a[7], vA.w, vB.w);
    }
    if (e < end) {
        uint4 vA = m[(size_t)esrc[e] * 8 + c];
        acc1(a[0], a[1], vA.x);
        acc1(a[2], a[3], vA.y);
        acc1(a[4], a[5], vA.z);
        acc1(a[6], a[7], vA.w);
    }
    #pragma unroll
    for (int d = 8; d <= 32; d <<= 1) {
        #pragma unroll
        for (int k = 0; k < 8; ++k) a[k] += __shfl_xor(a[k], d);
    }
    // lane (sub,c) holds full sums of channels c*8..c*8+7
    float4 w0 = ((const float4*)w3s)[c * 2];
    float4 w1 = ((const float4*)w3s)[c * 2 + 1];
    float partial = ftanh(a[0]) * w0.x + ftanh(a[1]) * w0.y
                  + ftanh(a[2]) * w0.z + ftanh(a[3]) * w0.w
                  + ftanh(a[4]) * w1.x + ftanh(a[5]) * w1.y
                  + ftanh(a[6]) * w1.z + ftanh(a[7]) * w1.w;
    partial += __shfl_xor(partial, 1);
    partial += __shfl_xor(partial, 2);
    partial += __shfl_xor(partial, 4);
    if (lane == 0) s3[n] = partial + w3s[64];
}

// ---------------------------------------------------------------------------
// w3s[i] = sum_o W3[o][i];  w3s[64] = sum(b3)
// ---------------------------------------------------------------------------
__global__ void w3s_kernel(const float* __restrict__ W3,
                           const float* __restrict__ b3,
                           float* __restrict__ w3s)
{
    int i = threadIdx.x;   // 64 threads
    float s = 0.f;
    for (int o = 0; o < 64; ++o) s += W3[o * 64 + i];
    w3s[i] = s;
    if (i == 0) {
        float bs = 0.f;
        for (int k = 0; k < 64; ++k) bs += b3[k];
        w3s[64] = bs;
    }
}

// ---------------------------------------------------------------------------
// per_graph[n2g[n]] += sum_{e in in(n)} s3[esrc[e]]   via CSR, LDS bins.
// ---------------------------------------------------------------------------
__global__ __launch_bounds__(256) void graph_reduce_kernel(
    const float* __restrict__ s3, const int* __restrict__ esrc,
    const int* __restrict__ rowptr, const int* __restrict__ n2g,
    float* __restrict__ out, int N)
{
    __shared__ float bins[NGRAPHS];
    int t = threadIdx.x;
    if (t < NGRAPHS) bins[t] = 0.f;
    __syncthreads();
    int n = blockIdx.x * 256 + t;
    if (n < N) {
        float acc = 0.f;
        for (int e = rowptr[n]; e < rowptr[n + 1]; ++e) acc += s3[esrc[e]];
        atomicAdd(&bins[n2g[n]], acc);
    }
    __syncthreads();
    if (t < NGRAPHS) unsafeAtomicAdd(&out[t], bins[t]);
}

// ---------------------------------------------------------------------------
extern "C" void kernel_launch(void* const* d_in, const int* in_sizes, int n_in,
                              void* d_out, int out_size, void* d_ws, size_t ws_size,
                              hipStream_t stream)
{
    const float* x   = (const float*)d_in[0];
    const float* W1  = (const float*)d_in[1];
    const float* b1  = (const float*)d_in[2];
    const float* W2  = (const float*)d_in[3];
    const float* b2  = (const float*)d_in[4];
    const float* W3  = (const float*)d_in[5];
    const float* b3  = (const float*)d_in[6];
    const int*   src = (const int*)d_in[7];
    const int*   dst = (const int*)d_in[8];
    const int*   n2g = (const int*)d_in[9];

    const int N = in_sizes[0] / 64;   // 100000
    const int E = in_sizes[7];        // 1600000
    const int K = (N + BSZ - 1) >> KBSHIFT;   // 196 buckets
    const int nb = (N + 255) / 256;

    // ---- workspace carve-up (256B-aligned) ----
    char* p = (char*)d_ws;
    auto carve = [&](size_t bytes) {
        char* r = p;
        p += (bytes + 255) & ~(size_t)255;
        return r;
    };
    unsigned* A     = (unsigned*)carve((size_t)N * 64 * 2);  // fp16 rows (12.8MB)
    unsigned* B     = (unsigned*)carve((size_t)N * 64 * 2);  // fp16 rows (12.8MB)
    float* s3b      = (float*)carve((size_t)N * sizeof(float));
    float* w3s      = (float*)carve(65 * sizeof(float));
    int*   bcnt     = (int*)carve(256 * sizeof(int));
    int*   bbase    = (int*)carve(257 * sizeof(int));
    int*   bcursor  = (int*)carve(256 * sizeof(int));
    int*   rowptr   = (int*)carve((size_t)(N + 1) * sizeof(int));
    int*   esrc     = (int*)carve((size_t)E * sizeof(int));
    // packed pairs (E*4B = 6.4MB) alias B: dead before gather_agg writes B.
    unsigned* pairs = (unsigned*)B;
    float* out      = (float*)d_out;

    const int gemm_blocks = N / 16;
    const int gath_blocks = (N + 3) / 4;
    const int chunk = (E + 255) / 256;

    // ---- CSR build: two-level counting sort ----
    hipMemsetAsync(bcnt, 0, 256 * sizeof(int), stream);
    bhist_kernel   <<<256, 256, 0, stream>>>(dst, bcnt, E, K);
    bscan_kernel   <<<1, 256, 0, stream>>>(bcnt, bbase, bcursor, rowptr, K, N, E);
    partition_kernel<<<256, 256, 0, stream>>>(src, dst, bcursor, pairs, E, K, chunk);
    bucket_build_kernel<<<K, BSZ, 0, stream>>>(pairs, bbase, rowptr, esrc, N);

    // ---- Layer 1: x (fp32) -> A (fp16) ----
    gemm_kernel<false, false><<<gemm_blocks, 256, 0, stream>>>(x, W1, b1, A);
    gather_agg_kernel<<<gath_blocks, 256, 0, stream>>>((const uint4*)A, esrc, rowptr, (uint4*)B, N);

    // ---- Layer 2: ftanh fused into fp16 input load ----
    gemm_kernel<true, true><<<gemm_blocks, 256, 0, stream>>>(B, W2, b2, A);

    // ---- Layer 3 collapsed + fused into gather 2 ----
    w3s_kernel<<<1, 64, 0, stream>>>(W3, b3, w3s);
    gather_s3_kernel<<<gath_blocks, 256, 0, stream>>>((const uint4*)A, esrc, rowptr, w3s, s3b, N);

    hipMemsetAsync(out, 0, NGRAPHS * sizeof(float), stream);
    graph_reduce_kernel<<<nb, 256, 0, stream>>>(s3b, esrc, rowptr, n2g, out, N);
}

// Round 7
// 292.602 us; speedup vs baseline: 10.2484x; 1.0178x over previous
//
#include <hip/hip_runtime.h>
#include <math.h>

#define NGRAPHS 8
#define KBSHIFT 8            // bucket = dst >> 8  (256 nodes per bucket)
#define BSZ 256              // nodes per bucket
#define KMAX 512             // LDS array sizing for bucket counts (K=391)
// NOTE: partition packs (dst&255)<<23 | src -> requires src < 2^23 (N=100k ok)

typedef _Float16 h2 __attribute__((ext_vector_type(2)));

__device__ __forceinline__ h2 as_h2(unsigned u) { return __builtin_bit_cast(h2, u); }
__device__ __forceinline__ unsigned pkf16(float a, float b) {
    auto v = __builtin_amdgcn_cvt_pkrtz(a, b);   // v_cvt_pkrtz_f16_f32
    return __builtin_bit_cast(unsigned, v);
}
// fast tanh: 1 - 2/(e^{2x}+1); exact at +-inf ends, ~1e-6 rel err (5 VALU)
__device__ __forceinline__ float ftanh(float x) {
    float t = __expf(2.0f * x);
    return 1.0f - 2.0f * __builtin_amdgcn_rcpf(t + 1.0f);
}
// accumulate two edges' packed-fp16 channel pair into fp32 accumulators
__device__ __forceinline__ void acc2(float& lo, float& hi, unsigned uA, unsigned uB) {
    const h2 ONES = {(_Float16)1.0f, (_Float16)1.0f};
    unsigned t0 = __builtin_amdgcn_perm(uB, uA, 0x05040100u);
    unsigned t1 = __builtin_amdgcn_perm(uB, uA, 0x07060302u);
    lo = __builtin_amdgcn_fdot2(as_h2(t0), ONES, lo, false);
    hi = __builtin_amdgcn_fdot2(as_h2(t1), ONES, hi, false);
}
__device__ __forceinline__ void acc1(float& lo, float& hi, unsigned u) {
    h2 hv = as_h2(u);
    lo += (float)hv.x;
    hi += (float)hv.y;
}

// ---------------------------------------------------------------------------
// GEMM-1: out[n][o] = sum_i in[n][i] * W[o][i] + b[o]  (fp32 in, fp16 out)
// ---------------------------------------------------------------------------
__global__ __launch_bounds__(256) void gemm1_kernel(
    const float* __restrict__ in, const float* __restrict__ W,
    const float* __restrict__ bias, unsigned* __restrict__ out)
{
    __shared__ float Wt[64 * 68];   // Wt[i*68 + o] = W[o][i]
    __shared__ float xs[16 * 65];
    const int t = threadIdx.x;
    const int node0 = blockIdx.x * 16;

    #pragma unroll
    for (int k = 0; k < 16; ++k) {
        int idx = k * 256 + t;
        int o = idx >> 6, i = idx & 63;
        Wt[i * 68 + o] = W[idx];
    }
    #pragma unroll
    for (int k = 0; k < 4; ++k) {
        int idx = k * 256 + t;
        int nl = idx >> 6, i = idx & 63;
        xs[nl * 65 + i] = in[node0 * 64 + idx];
    }
    __syncthreads();

    const int nl = t >> 4;
    const int o4 = t & 15;
    float4 acc = make_float4(0.f, 0.f, 0.f, 0.f);
    #pragma unroll
    for (int i = 0; i < 64; ++i) {
        float xv = xs[nl * 65 + i];
        float4 wv = *(const float4*)&Wt[i * 68 + o4 * 4];
        acc.x += xv * wv.x;
        acc.y += xv * wv.y;
        acc.z += xv * wv.z;
        acc.w += xv * wv.w;
    }
    float4 b4 = ((const float4*)bias)[o4];
    acc.x += b4.x; acc.y += b4.y; acc.z += b4.z; acc.w += b4.w;
    uint2 o;
    o.x = pkf16(acc.x, acc.y);
    o.y = pkf16(acc.z, acc.w);
    ((uint2*)out)[(node0 + nl) * 16 + o4] = o;   // fp16 row = 128B
}

// ---------------------------------------------------------------------------
// Bucket histogram: bcnt[k] = #edges with dst>>8 == k.
// ---------------------------------------------------------------------------
__global__ __launch_bounds__(256) void bhist_kernel(
    const int* __restrict__ dst, int* __restrict__ bcnt, int E, int K)
{
    __shared__ int h[KMAX];
    int t = threadIdx.x;
    h[t] = 0; h[t + 256] = 0;
    __syncthreads();
    for (int e = blockIdx.x * 256 + t; e < E; e += gridDim.x * 256)
        atomicAdd(&h[dst[e] >> KBSHIFT], 1);
    __syncthreads();
    for (int k = t; k < K; k += 256)
        if (h[k] > 0) atomicAdd(&bcnt[k], h[k]);
}

// ---------------------------------------------------------------------------
// Exclusive scan of K (<=512) bucket counts -> bbase[0..K], bcursor=bbase.
// Also computes w3s (fused; threads idle otherwise): w3s[i]=colsum W3, [64]=sum b3
// ---------------------------------------------------------------------------
__global__ __launch_bounds__(512) void bscan_w3s_kernel(
    const int* __restrict__ bcnt, int* __restrict__ bbase,
    int* __restrict__ bcursor, int* __restrict__ rowptr,
    const float* __restrict__ W3, const float* __restrict__ b3,
    float* __restrict__ w3s, int K, int N, int E)
{
    __shared__ int tmp[512];
    int t = threadIdx.x;
    int v = (t < K) ? bcnt[t] : 0;
    tmp[t] = v;
    __syncthreads();
    #pragma unroll
    for (int off = 1; off < 512; off <<= 1) {
        int u = (t >= off) ? tmp[t - off] : 0;
        __syncthreads();
        tmp[t] += u;
        __syncthreads();
    }
    int excl = tmp[t] - v;
    if (t < K) { bbase[t] = excl; bcursor[t] = excl; }
    if (t == 0) { bbase[K] = E; rowptr[N] = E; }
    // fused w3s
    if (t < 64) {
        float s = 0.f;
        for (int o = 0; o < 64; ++o) s += W3[o * 64 + t];
        w3s[t] = s;
    }
    if (t == 64) {
        float bs = 0.f;
        for (int k = 0; k < 64; ++k) bs += b3[k];
        w3s[64] = bs;
    }
}

// ---------------------------------------------------------------------------
// Partition edges into buckets; packed pair = (dst&255)<<23 | src.
// ---------------------------------------------------------------------------
__global__ __launch_bounds__(256) void partition_kernel(
    const int* __restrict__ src, const int* __restrict__ dst,
    int* __restrict__ bcursor, unsigned* __restrict__ pairs, int E, int K, int chunk)
{
    __shared__ int h[KMAX];
    __shared__ int base[KMAX];
    __shared__ int c[KMAX];
    int t = threadIdx.x;
    int lo = blockIdx.x * chunk;
    int hi = lo + chunk; if (hi > E) hi = E;

    h[t] = 0; h[t + 256] = 0;
    c[t] = 0; c[t + 256] = 0;
    __syncthreads();
    for (int e = lo + t; e < hi; e += 256)
        atomicAdd(&h[dst[e] >> KBSHIFT], 1);
    __syncthreads();
    for (int k = t; k < K; k += 256)
        base[k] = (h[k] > 0) ? atomicAdd(&bcursor[k], h[k]) : 0;
    __syncthreads();
    for (int e = lo + t; e < hi; e += 256) {
        int d = dst[e];
        int k = d >> KBSHIFT;
        int pos = atomicAdd(&c[k], 1);
        pairs[base[k] + pos] = ((unsigned)(d & (BSZ - 1)) << 23) | (unsigned)src[e];
    }
}

// ---------------------------------------------------------------------------
// Per-bucket CSR finalize (391 blocks x 256): LDS hist -> scan -> rowptr +
// esrc scatter into the bucket's contiguous window.
// ---------------------------------------------------------------------------
__global__ __launch_bounds__(256) void bucket_build_kernel(
    const unsigned* __restrict__ pairs, const int* __restrict__ bbase,
    int* __restrict__ rowptr, int* __restrict__ esrc, int N)
{
    __shared__ int cnt[BSZ];
    __shared__ int tmp[BSZ];
    __shared__ int cur[BSZ];
    int k = blockIdx.x;
    int t = threadIdx.x;
    int ebase = bbase[k], eend = bbase[k + 1];

    cnt[t] = 0;
    __syncthreads();
    for (int e = ebase + t; e < eend; e += BSZ)
        atomicAdd(&cnt[pairs[e] >> 23], 1);
    __syncthreads();

    int v = cnt[t];
    tmp[t] = v;
    __syncthreads();
    #pragma unroll
    for (int off = 1; off < BSZ; off <<= 1) {
        int u = (t >= off) ? tmp[t - off] : 0;
        __syncthreads();
        tmp[t] += u;
        __syncthreads();
    }
    int excl = tmp[t] - v;
    cur[t] = excl;
    int n = (k << KBSHIFT) + t;
    if (n < N) rowptr[n] = ebase + excl;
    __syncthreads();

    for (int e = ebase + t; e < eend; e += BSZ) {
        unsigned p = pairs[e];
        int pos = atomicAdd(&cur[p >> 23], 1);
        esrc[ebase + pos] = (int)(p & 0x7fffffu);
    }
}

// ---------------------------------------------------------------------------
// FUSED gather-1 + tanh + GEMM-2: out[n] = tanh(sum_inedges m1[src]) @ W2.T + b2
// One wave per node (grid-stride). Gather as before; then sub0 lanes tanh+pack
// the h row into a per-wave LDS buffer (same-wave LDS RAW, no barrier), and
// each lane computes one output channel with 32 v_dot2_f32_f16 against
// fp16-packed W2 staged once per block.
// ---------------------------------------------------------------------------
__global__ __launch_bounds__(256) void gather_gemm2_kernel(
    const uint4* __restrict__ m, const int* __restrict__ esrc,
    const int* __restrict__ rowptr, const float* __restrict__ W2,
    const float* __restrict__ b2, unsigned* __restrict__ out, int N, int stride)
{
    __shared__ unsigned Wt2[32 * 65];  // [i2*65+o] = pk(W2[o][2i2], W2[o][2i2+1])
    __shared__ unsigned hbuf[4 * 32];  // per-wave packed h row (64 ch = 32 uints)
    int t = threadIdx.x;

    const float2* W2f2 = (const float2*)W2;
    for (int idx = t; idx < 2048; idx += 256) {
        int o = idx >> 5, i2 = idx & 31;
        float2 w = W2f2[o * 32 + i2];
        Wt2[i2 * 65 + o] = pkf16(w.x, w.y);
    }
    __syncthreads();

    int wid = t >> 6, lane = t & 63;
    int sub = lane >> 3, c = lane & 7;
    float myb = b2[lane];

    for (int n = blockIdx.x * 4 + wid; n < N; n += stride) {
        int beg = rowptr[n], end = rowptr[n + 1];
        float a[8] = {0.f, 0.f, 0.f, 0.f, 0.f, 0.f, 0.f, 0.f};
        int e = beg + sub;
        for (; e + 8 < end; e += 16) {
            int sA = esrc[e], sB = esrc[e + 8];
            uint4 vA = m[(size_t)sA * 8 + c];
            uint4 vB = m[(size_t)sB * 8 + c];
            acc2(a[0], a[1], vA.x, vB.x);
            acc2(a[2], a[3], vA.y, vB.y);
            acc2(a[4], a[5], vA.z, vB.z);
            acc2(a[6], a[7], vA.w, vB.w);
        }
        if (e < end) {
            uint4 vA = m[(size_t)esrc[e] * 8 + c];
            acc1(a[0], a[1], vA.x);
            acc1(a[2], a[3], vA.y);
            acc1(a[4], a[5], vA.z);
            acc1(a[6], a[7], vA.w);
        }
        #pragma unroll
        for (int d = 8; d <= 32; d <<= 1) {
            #pragma unroll
            for (int k = 0; k < 8; ++k) a[k] += __shfl_xor(a[k], d);
        }
        // h = tanh(agg): sub0 lanes pack their 8 channels (pairs 2i2,2i2+1)
        if (sub == 0) {
            #pragma unroll
            for (int k2 = 0; k2 < 4; ++k2)
                hbuf[wid * 32 + c * 4 + k2] =
                    pkf16(ftanh(a[2 * k2]), ftanh(a[2 * k2 + 1]));
        }
        // same-wave LDS write->read: in-order, compiler inserts lgkmcnt
        float acc = myb;
        #pragma unroll
        for (int i2 = 0; i2 < 32; ++i2) {
            unsigned hv = hbuf[wid * 32 + i2];          // broadcast
            unsigned wv = Wt2[i2 * 65 + lane];          // stride-1, 2-way free
            acc = __builtin_amdgcn_fdot2(as_h2(hv), as_h2(wv), acc, false);
        }
        // pack pairwise: even lanes write (o, o+1)
        float nb = __shfl_down(acc, 1);
        if (!(lane & 1)) out[(size_t)n * 32 + (lane >> 1)] = pkf16(acc, nb);
    }
}

// ---------------------------------------------------------------------------
// Gather + collapsed layer 3: s3[n] = ftanh(sum_row m2) . w3s + w3s[64]
// ---------------------------------------------------------------------------
__global__ __launch_bounds__(256) void gather_s3_kernel(
    const uint4* __restrict__ m, const int* __restrict__ esrc,
    const int* __restrict__ rowptr, const float* __restrict__ w3s,
    float* __restrict__ s3, int N)
{
    int n = blockIdx.x * 4 + (threadIdx.x >> 6);
    if (n >= N) return;
    int lane = threadIdx.x & 63;
    int sub = lane >> 3, c = lane & 7;
    int beg = rowptr[n], end = rowptr[n + 1];
    float a[8] = {0.f, 0.f, 0.f, 0.f, 0.f, 0.f, 0.f, 0.f};
    int e = beg + sub;
    for (; e + 8 < end; e += 16) {
        int sA = esrc[e], sB = esrc[e + 8];
        uint4 vA = m[(size_t)sA * 8 + c];
        uint4 vB = m[(size_t)sB * 8 + c];
        acc2(a[0], a[1], vA.x, vB.x);
        acc2(a[2], a[3], vA.y, vB.y);
        acc2(a[4], a[5], vA.z, vB.z);
        acc2(a[6], a[7], vA.w, vB.w);
    }
    if (e < end) {
        uint4 vA = m[(size_t)esrc[e] * 8 + c];
        acc1(a[0], a[1], vA.x);
        acc1(a[2], a[3], vA.y);
        acc1(a[4], a[5], vA.z);
        acc1(a[6], a[7], vA.w);
    }
    #pragma unroll
    for (int d = 8; d <= 32; d <<= 1) {
        #pragma unroll
        for (int k = 0; k < 8; ++k) a[k] += __shfl_xor(a[k], d);
    }
    float4 w0 = ((const float4*)w3s)[c * 2];
    float4 w1 = ((const float4*)w3s)[c * 2 + 1];
    float partial = ftanh(a[0]) * w0.x + ftanh(a[1]) * w0.y
                  + ftanh(a[2]) * w0.z + ftanh(a[3]) * w0.w
                  + ftanh(a[4]) * w1.x + ftanh(a[5]) * w1.y
                  + ftanh(a[6]) * w1.z + ftanh(a[7]) * w1.w;
    partial += __shfl_xor(partial, 1);
    partial += __shfl_xor(partial, 2);
    partial += __shfl_xor(partial, 4);
    if (lane == 0) s3[n] = partial + w3s[64];
}

// ---------------------------------------------------------------------------
// per_graph[n2g[n]] += sum_{e in in(n)} s3[esrc[e]]   via CSR, LDS bins.
// ---------------------------------------------------------------------------
__global__ __launch_bounds__(256) void graph_reduce_kernel(
    const float* __restrict__ s3, const int* __restrict__ esrc,
    const int* __restrict__ rowptr, const int* __restrict__ n2g,
    float* __restrict__ out, int N)
{
    __shared__ float bins[NGRAPHS];
    int t = threadIdx.x;
    if (t < NGRAPHS) bins[t] = 0.f;
    __syncthreads();
    int n = blockIdx.x * 256 + t;
    if (n < N) {
        float acc = 0.f;
        for (int e = rowptr[n]; e < rowptr[n + 1]; ++e) acc += s3[esrc[e]];
        atomicAdd(&bins[n2g[n]], acc);
    }
    __syncthreads();
    if (t < NGRAPHS) unsafeAtomicAdd(&out[t], bins[t]);
}

// ---------------------------------------------------------------------------
extern "C" void kernel_launch(void* const* d_in, const int* in_sizes, int n_in,
                              void* d_out, int out_size, void* d_ws, size_t ws_size,
                              hipStream_t stream)
{
    const float* x   = (const float*)d_in[0];
    const float* W1  = (const float*)d_in[1];
    const float* b1  = (const float*)d_in[2];
    const float* W2  = (const float*)d_in[3];
    const float* b2  = (const float*)d_in[4];
    const float* W3  = (const float*)d_in[5];
    const float* b3  = (const float*)d_in[6];
    const int*   src = (const int*)d_in[7];
    const int*   dst = (const int*)d_in[8];
    const int*   n2g = (const int*)d_in[9];

    const int N = in_sizes[0] / 64;   // 100000
    const int E = in_sizes[7];        // 1600000
    const int K = (N + BSZ - 1) >> KBSHIFT;   // 391 buckets
    const int nb = (N + 255) / 256;

    // ---- workspace carve-up (256B-aligned) ----
    char* p = (char*)d_ws;
    auto carve = [&](size_t bytes) {
        char* r = p;
        p += (bytes + 255) & ~(size_t)255;
        return r;
    };
    unsigned* A     = (unsigned*)carve((size_t)N * 64 * 2);  // m1 fp16 rows
    unsigned* B     = (unsigned*)carve((size_t)N * 64 * 2);  // m2 fp16 rows
    float* s3b      = (float*)carve((size_t)N * sizeof(float));
    float* w3s      = (float*)carve(65 * sizeof(float));
    int*   bcnt     = (int*)carve(KMAX * sizeof(int));
    int*   bbase    = (int*)carve((KMAX + 1) * sizeof(int));
    int*   bcursor  = (int*)carve(KMAX * sizeof(int));
    int*   rowptr   = (int*)carve((size_t)(N + 1) * sizeof(int));
    int*   esrc     = (int*)carve((size_t)E * sizeof(int));
    // packed pairs (E*4B = 6.4MB) alias B: dead before gather_gemm2 writes B.
    unsigned* pairs = (unsigned*)B;
    float* out      = (float*)d_out;

    const int gemm_blocks = N / 16;
    const int gath_blocks = (N + 3) / 4;
    const int PART_BLOCKS = 512;
    const int chunk = (E + PART_BLOCKS - 1) / PART_BLOCKS;
    const int FUSED_BLOCKS = 2048;

    // ---- CSR build: two-level counting sort ----
    (void)hipMemsetAsync(bcnt, 0, KMAX * sizeof(int), stream);
    bhist_kernel   <<<256, 256, 0, stream>>>(dst, bcnt, E, K);
    bscan_w3s_kernel<<<1, 512, 0, stream>>>(bcnt, bbase, bcursor, rowptr,
                                            W3, b3, w3s, K, N, E);
    partition_kernel<<<PART_BLOCKS, 256, 0, stream>>>(src, dst, bcursor, pairs, E, K, chunk);
    bucket_build_kernel<<<K, BSZ, 0, stream>>>(pairs, bbase, rowptr, esrc, N);

    // ---- Layer 1: x (fp32) -> A (m1, fp16) ----
    gemm1_kernel<<<gemm_blocks, 256, 0, stream>>>(x, W1, b1, A);

    // ---- Fused: gather-1 + tanh + GEMM-2 -> B (m2, fp16) ----
    gather_gemm2_kernel<<<FUSED_BLOCKS, 256, 0, stream>>>(
        (const uint4*)A, esrc, rowptr, W2, b2, B, N, FUSED_BLOCKS * 4);

    // ---- Layer 3 collapsed + fused into gather 2 ----
    gather_s3_kernel<<<gath_blocks, 256, 0, stream>>>((const uint4*)B, esrc, rowptr, w3s, s3b, N);

    (void)hipMemsetAsync(out, 0, NGRAPHS * sizeof(float), stream);
    graph_reduce_kernel<<<nb, 256, 0, stream>>>(s3b, esrc, rowptr, n2g, out, N);
}

// Round 8
// 280.491 us; speedup vs baseline: 10.6909x; 1.0432x over previous
//
#include <hip/hip_runtime.h>
#include <math.h>

#define NGRAPHS 8
#define KBSHIFT 8            // bucket = dst >> 8  (256 nodes per bucket)
#define BSZ 256              // nodes per bucket
#define KMAX 512             // >= K = ceil(N/BSZ) = 391
#define PCHUNK 3125          // edges per partition block (stage fits LDS)
// NOTE: partition packs (dst&255)<<23 | src -> requires src < 2^23 (N=100k ok)

typedef _Float16 h2 __attribute__((ext_vector_type(2)));

__device__ __forceinline__ h2 as_h2(unsigned u) { return __builtin_bit_cast(h2, u); }
__device__ __forceinline__ unsigned pkf16(float a, float b) {
    auto v = __builtin_amdgcn_cvt_pkrtz(a, b);   // v_cvt_pkrtz_f16_f32
    return __builtin_bit_cast(unsigned, v);
}
// fast tanh: 1 - 2/(e^{2x}+1); exact at +-inf ends, ~1e-6 rel err
__device__ __forceinline__ float ftanh(float x) {
    float t = __expf(2.0f * x);
    return 1.0f - 2.0f * __builtin_amdgcn_rcpf(t + 1.0f);
}
// accumulate two edges' packed-fp16 channel pair into fp32 accumulators
__device__ __forceinline__ void acc2(float& lo, float& hi, unsigned uA, unsigned uB) {
    const h2 ONES = {(_Float16)1.0f, (_Float16)1.0f};
    unsigned t0 = __builtin_amdgcn_perm(uB, uA, 0x05040100u);
    unsigned t1 = __builtin_amdgcn_perm(uB, uA, 0x07060302u);
    lo = __builtin_amdgcn_fdot2(as_h2(t0), ONES, lo, false);
    hi = __builtin_amdgcn_fdot2(as_h2(t1), ONES, hi, false);
}
__device__ __forceinline__ void acc1(float& lo, float& hi, unsigned u) {
    h2 hv = as_h2(u);
    lo += (float)hv.x;
    hi += (float)hv.y;
}

// ---------------------------------------------------------------------------
// GEMM-1: out[n][o] = sum_i in[n][i] * W[o][i] + b[o]  (fp32 in, fp16 out)
// Also zeroes bcnt (runs before bhist in the stream).
// ---------------------------------------------------------------------------
__global__ __launch_bounds__(256) void gemm1_kernel(
    const float* __restrict__ in, const float* __restrict__ W,
    const float* __restrict__ bias, unsigned* __restrict__ out,
    int* __restrict__ bcnt)
{
    __shared__ float Wt[64 * 68];   // Wt[i*68 + o] = W[o][i]
    __shared__ float xs[16 * 65];
    const int t = threadIdx.x;
    const int node0 = blockIdx.x * 16;
    if (blockIdx.x == 0) { bcnt[t] = 0; bcnt[t + 256] = 0; }

    #pragma unroll
    for (int k = 0; k < 16; ++k) {
        int idx = k * 256 + t;
        int o = idx >> 6, i = idx & 63;
        Wt[i * 68 + o] = W[idx];
    }
    #pragma unroll
    for (int k = 0; k < 4; ++k) {
        int idx = k * 256 + t;
        int nl = idx >> 6, i = idx & 63;
        xs[nl * 65 + i] = in[node0 * 64 + idx];
    }
    __syncthreads();

    const int nl = t >> 4;
    const int o4 = t & 15;
    float4 acc = make_float4(0.f, 0.f, 0.f, 0.f);
    #pragma unroll
    for (int i = 0; i < 64; ++i) {
        float xv = xs[nl * 65 + i];
        float4 wv = *(const float4*)&Wt[i * 68 + o4 * 4];
        acc.x += xv * wv.x;
        acc.y += xv * wv.y;
        acc.z += xv * wv.z;
        acc.w += xv * wv.w;
    }
    float4 b4 = ((const float4*)bias)[o4];
    acc.x += b4.x; acc.y += b4.y; acc.z += b4.z; acc.w += b4.w;
    uint2 o;
    o.x = pkf16(acc.x, acc.y);
    o.y = pkf16(acc.z, acc.w);
    ((uint2*)out)[(node0 + nl) * 16 + o4] = o;
}

// ---------------------------------------------------------------------------
// Bucket histogram: bcnt[k] = #edges with dst>>8 == k.
// ---------------------------------------------------------------------------
__global__ __launch_bounds__(256) void bhist_kernel(
    const int* __restrict__ dst, int* __restrict__ bcnt, int E, int K)
{
    __shared__ int h[KMAX];
    int t = threadIdx.x;
    h[t] = 0; h[t + 256] = 0;
    __syncthreads();
    for (int e = blockIdx.x * 256 + t; e < E; e += gridDim.x * 256)
        atomicAdd(&h[dst[e] >> KBSHIFT], 1);
    __syncthreads();
    for (int k = t; k < K; k += 256)
        if (h[k] > 0) atomicAdd(&bcnt[k], h[k]);
}

// ---------------------------------------------------------------------------
// Exclusive scan of K (<=512) bucket counts -> bbase[0..K], bcursor=bbase.
// Fused: w3s[i] = colsum W3, w3s[64] = sum b3.
// ---------------------------------------------------------------------------
__global__ __launch_bounds__(512) void bscan_w3s_kernel(
    const int* __restrict__ bcnt, int* __restrict__ bbase,
    int* __restrict__ bcursor, int* __restrict__ rowptr,
    const float* __restrict__ W3, const float* __restrict__ b3,
    float* __restrict__ w3s, int K, int N, int E)
{
    __shared__ int tmp[512];
    int t = threadIdx.x;
    int v = (t < K) ? bcnt[t] : 0;
    tmp[t] = v;
    __syncthreads();
    #pragma unroll
    for (int off = 1; off < 512; off <<= 1) {
        int u = (t >= off) ? tmp[t - off] : 0;
        __syncthreads();
        tmp[t] += u;
        __syncthreads();
    }
    int excl = tmp[t] - v;
    if (t < K) { bbase[t] = excl; bcursor[t] = excl; }
    if (t == 0) { bbase[K] = E; rowptr[N] = E; }
    if (t < 64) {
        float s = 0.f;
        for (int o = 0; o < 64; ++o) s += W3[o * 64 + t];
        w3s[t] = s;
    }
    if (t == 64) {
        float bs = 0.f;
        for (int k = 0; k < 64; ++k) bs += b3[k];
        w3s[64] = bs;
    }
}

// ---------------------------------------------------------------------------
// Partition edges into buckets with LDS-staged, bucket-ordered output:
// per block: hist -> in-LDS scan -> stage pairs bucket-sorted in LDS ->
// flush as contiguous per-bucket runs (coalesced ~32B runs, ~2x line amp
// instead of ~16x from direct 4B scatters).
// ---------------------------------------------------------------------------
__global__ __launch_bounds__(512) void partition_kernel(
    const int* __restrict__ src, const int* __restrict__ dst,
    int* __restrict__ bcursor, unsigned* __restrict__ pairs, int E, int K)
{
    __shared__ int h[512];          // hist, then inclusive-scan buffer
    __shared__ int sh[512];         // exclusive within-block start per bucket
    __shared__ int base[512];       // global base of this block's run
    __shared__ int cur[512];        // within-block bucket cursor
    __shared__ unsigned val[PCHUNK + 3];
    __shared__ unsigned short bk[PCHUNK + 3];
    const int t = threadIdx.x;
    const int lo = blockIdx.x * PCHUNK;
    int hi = lo + PCHUNK; if (hi > E) hi = E;
    const int cnt = hi - lo;

    h[t] = 0; cur[t] = 0;
    __syncthreads();
    for (int e = lo + t; e < hi; e += 512)
        atomicAdd(&h[dst[e] >> KBSHIFT], 1);
    __syncthreads();
    int v = h[t];
    int x = v;
    #pragma unroll
    for (int off = 1; off < 512; off <<= 1) {
        int u = (t >= off) ? h[t - off] : 0;
        __syncthreads();
        x += u;
        h[t] = x;
        __syncthreads();
    }
    sh[t] = x - v;                                   // exclusive scan
    base[t] = (t < K && v > 0) ? atomicAdd(&bcursor[t], v) : 0;
    __syncthreads();
    for (int e = lo + t; e < hi; e += 512) {
        int d = dst[e];
        int k = d >> KBSHIFT;
        int pos = atomicAdd(&cur[k], 1);
        int j = sh[k] + pos;
        val[j] = ((unsigned)(d & (BSZ - 1)) << 23) | (unsigned)src[e];
        bk[j] = (unsigned short)k;
    }
    __syncthreads();
    for (int j = t; j < cnt; j += 512) {
        int k = bk[j];
        pairs[base[k] + (j - sh[k])] = val[j];       // coalesced per-bucket runs
    }
}

// ---------------------------------------------------------------------------
// Per-bucket CSR finalize: LDS hist -> scan -> rowptr + esrc scatter into
// the bucket's contiguous window (every line written by one block only).
// ---------------------------------------------------------------------------
__global__ __launch_bounds__(256) void bucket_build_kernel(
    const unsigned* __restrict__ pairs, const int* __restrict__ bbase,
    int* __restrict__ rowptr, int* __restrict__ esrc, int N)
{
    __shared__ int cnt[BSZ];
    __shared__ int tmp[BSZ];
    __shared__ int cur[BSZ];
    int k = blockIdx.x;
    int t = threadIdx.x;
    int ebase = bbase[k], eend = bbase[k + 1];

    cnt[t] = 0;
    __syncthreads();
    for (int e = ebase + t; e < eend; e += BSZ)
        atomicAdd(&cnt[pairs[e] >> 23], 1);
    __syncthreads();

    int v = cnt[t];
    tmp[t] = v;
    __syncthreads();
    #pragma unroll
    for (int off = 1; off < BSZ; off <<= 1) {
        int u = (t >= off) ? tmp[t - off] : 0;
        __syncthreads();
        tmp[t] += u;
        __syncthreads();
    }
    int excl = tmp[t] - v;
    cur[t] = excl;
    int n = (k << KBSHIFT) + t;
    if (n < N) rowptr[n] = ebase + excl;
    __syncthreads();

    for (int e = ebase + t; e < eend; e += BSZ) {
        unsigned p = pairs[e];
        int pos = atomicAdd(&cur[p >> 23], 1);
        esrc[ebase + pos] = (int)(p & 0x7fffffu);
    }
}

// ---------------------------------------------------------------------------
// FUSED gather-1 + tanh + GEMM-2, 2 nodes per wave (32 lanes each):
// gather with 4 edge slots x pairing (8 edges in flight/node), xor-reduce
// (8,16) within each half; W2 column cached in 32 VGPRs per lane; h row
// broadcast via __shfl; 64 fdot2 per node pair. Zero LDS.
// ---------------------------------------------------------------------------
__global__ __launch_bounds__(256) void gather_gemm2_kernel(
    const uint4* __restrict__ m, const int* __restrict__ esrc,
    const int* __restrict__ rowptr, const float* __restrict__ W2,
    const float* __restrict__ b2, unsigned* __restrict__ out, int N)
{
    const int t = threadIdx.x;
    const int lane = t & 63;
    const int l32 = t & 31;
    const int sub = l32 >> 3, c = l32 & 7;

    unsigned w2r[32];   // packed fp16 column for output channel `lane`
    {
        const float4* wrow = (const float4*)(W2 + lane * 64);
        #pragma unroll
        for (int i4 = 0; i4 < 16; ++i4) {
            float4 w = wrow[i4];
            w2r[2 * i4]     = pkf16(w.x, w.y);
            w2r[2 * i4 + 1] = pkf16(w.z, w.w);
        }
    }
    const float myb = b2[lane];
    const int ngroups = (N + 7) >> 3;

    for (int g = blockIdx.x; g < ngroups; g += gridDim.x) {
        int n = g * 8 + (t >> 5);          // this half's node
        float a[8] = {0.f,0.f,0.f,0.f,0.f,0.f,0.f,0.f};
        if (n < N) {
            int beg = rowptr[n], end = rowptr[n + 1];
            int e = beg + sub;
            for (; e + 4 < end; e += 8) {
                int sA = esrc[e], sB = esrc[e + 4];
                uint4 vA = m[(size_t)sA * 8 + c];
                uint4 vB = m[(size_t)sB * 8 + c];
                acc2(a[0], a[1], vA.x, vB.x);
                acc2(a[2], a[3], vA.y, vB.y);
                acc2(a[4], a[5], vA.z, vB.z);
                acc2(a[6], a[7], vA.w, vB.w);
            }
            if (e < end) {
                uint4 vA = m[(size_t)esrc[e] * 8 + c];
                acc1(a[0], a[1], vA.x);
                acc1(a[2], a[3], vA.y);
                acc1(a[4], a[5], vA.z);
                acc1(a[6], a[7], vA.w);
            }
        }
        #pragma unroll
        for (int d = 8; d <= 16; d <<= 1) {
            #pragma unroll
            for (int k = 0; k < 8; ++k) a[k] += __shfl_xor(a[k], d);
        }
        // h = tanh(agg), packed: lane holds uints c*4..c*4+3 of its node's row
        unsigned hp0 = pkf16(ftanh(a[0]), ftanh(a[1]));
        unsigned hp1 = pkf16(ftanh(a[2]), ftanh(a[3]));
        unsigned hp2 = pkf16(ftanh(a[4]), ftanh(a[5]));
        unsigned hp3 = pkf16(ftanh(a[6]), ftanh(a[7]));
        // GEMM: lane computes channel `lane` for both nodes of its wave
        float accA = myb, accB = myb;
        #pragma unroll
        for (int q = 0; q < 8; ++q) {
            unsigned hA0 = __shfl(hp0, q), hB0 = __shfl(hp0, 32 + q);
            unsigned hA1 = __shfl(hp1, q), hB1 = __shfl(hp1, 32 + q);
            unsigned hA2 = __shfl(hp2, q), hB2 = __shfl(hp2, 32 + q);
            unsigned hA3 = __shfl(hp3, q), hB3 = __shfl(hp3, 32 + q);
            accA = __builtin_amdgcn_fdot2(as_h2(hA0), as_h2(w2r[q*4+0]), accA, false);
            accA = __builtin_amdgcn_fdot2(as_h2(hA1), as_h2(w2r[q*4+1]), accA, false);
            accA = __builtin_amdgcn_fdot2(as_h2(hA2), as_h2(w2r[q*4+2]), accA, false);
            accA = __builtin_amdgcn_fdot2(as_h2(hA3), as_h2(w2r[q*4+3]), accA, false);
            accB = __builtin_amdgcn_fdot2(as_h2(hB0), as_h2(w2r[q*4+0]), accB, false);
            accB = __builtin_amdgcn_fdot2(as_h2(hB1), as_h2(w2r[q*4+1]), accB, false);
            accB = __builtin_amdgcn_fdot2(as_h2(hB2), as_h2(w2r[q*4+2]), accB, false);
            accB = __builtin_amdgcn_fdot2(as_h2(hB3), as_h2(w2r[q*4+3]), accB, false);
        }
        int nA = g * 8 + 2 * (t >> 6);
        int nB = nA + 1;
        float nbA = __shfl_down(accA, 1);
        float nbB = __shfl_down(accB, 1);
        if (!(lane & 1)) {
            if (nA < N) out[(size_t)nA * 32 + (lane >> 1)] = pkf16(accA, nbA);
            if (nB < N) out[(size_t)nB * 32 + (lane >> 1)] = pkf16(accB, nbB);
        }
    }
}

// ---------------------------------------------------------------------------
// Gather + collapsed layer 3, 2 nodes per wave:
// s3[n] = ftanh(sum_row m2) . w3s + w3s[64].  Also zeroes d_out.
// ---------------------------------------------------------------------------
__global__ __launch_bounds__(256) void gather_s3_kernel(
    const uint4* __restrict__ m, const int* __restrict__ esrc,
    const int* __restrict__ rowptr, const float* __restrict__ w3s,
    float* __restrict__ s3, float* __restrict__ outz, int N)
{
    const int t = threadIdx.x;
    if (blockIdx.x == 0 && t < NGRAPHS) outz[t] = 0.f;
    const int n = blockIdx.x * 8 + (t >> 5);
    const int l32 = t & 31;
    const int sub = l32 >> 3, c = l32 & 7;
    float a[8] = {0.f,0.f,0.f,0.f,0.f,0.f,0.f,0.f};
    if (n < N) {
        int beg = rowptr[n], end = rowptr[n + 1];
        int e = beg + sub;
        for (; e + 4 < end; e += 8) {
            int sA = esrc[e], sB = esrc[e + 4];
            uint4 vA = m[(size_t)sA * 8 + c];
            uint4 vB = m[(size_t)sB * 8 + c];
            acc2(a[0], a[1], vA.x, vB.x);
            acc2(a[2], a[3], vA.y, vB.y);
            acc2(a[4], a[5], vA.z, vB.z);
            acc2(a[6], a[7], vA.w, vB.w);
        }
        if (e < end) {
            uint4 vA = m[(size_t)esrc[e] * 8 + c];
            acc1(a[0], a[1], vA.x);
            acc1(a[2], a[3], vA.y);
            acc1(a[4], a[5], vA.z);
            acc1(a[6], a[7], vA.w);
        }
    }
    #pragma unroll
    for (int d = 8; d <= 16; d <<= 1) {
        #pragma unroll
        for (int k = 0; k < 8; ++k) a[k] += __shfl_xor(a[k], d);
    }
    float4 w0 = ((const float4*)w3s)[c * 2];
    float4 w1 = ((const float4*)w3s)[c * 2 + 1];
    float partial = ftanh(a[0]) * w0.x + ftanh(a[1]) * w0.y
                  + ftanh(a[2]) * w0.z + ftanh(a[3]) * w0.w
                  + ftanh(a[4]) * w1.x + ftanh(a[5]) * w1.y
                  + ftanh(a[6]) * w1.z + ftanh(a[7]) * w1.w;
    partial += __shfl_xor(partial, 1);
    partial += __shfl_xor(partial, 2);
    partial += __shfl_xor(partial, 4);
    if (l32 == 0 && n < N) s3[n] = partial + w3s[64];
}

// ---------------------------------------------------------------------------
// per_graph[n2g[n]] += sum_{e in in(n)} s3[esrc[e]]   via CSR, LDS bins.
// ---------------------------------------------------------------------------
__global__ __launch_bounds__(256) void graph_reduce_kernel(
    const float* __restrict__ s3, const int* __restrict__ esrc,
    const int* __restrict__ rowptr, const int* __restrict__ n2g,
    float* __restrict__ out, int N)
{
    __shared__ float bins[NGRAPHS];
    int t = threadIdx.x;
    if (t < NGRAPHS) bins[t] = 0.f;
    __syncthreads();
    int n = blockIdx.x * 256 + t;
    if (n < N) {
        float acc = 0.f;
        for (int e = rowptr[n]; e < rowptr[n + 1]; ++e) acc += s3[esrc[e]];
        atomicAdd(&bins[n2g[n]], acc);
    }
    __syncthreads();
    if (t < NGRAPHS) unsafeAtomicAdd(&out[t], bins[t]);
}

// ---------------------------------------------------------------------------
extern "C" void kernel_launch(void* const* d_in, const int* in_sizes, int n_in,
                              void* d_out, int out_size, void* d_ws, size_t ws_size,
                              hipStream_t stream)
{
    const float* x   = (const float*)d_in[0];
    const float* W1  = (const float*)d_in[1];
    const float* b1  = (const float*)d_in[2];
    const float* W2  = (const float*)d_in[3];
    const float* b2  = (const float*)d_in[4];
    const float* W3  = (const float*)d_in[5];
    const float* b3  = (const float*)d_in[6];
    const int*   src = (const int*)d_in[7];
    const int*   dst = (const int*)d_in[8];
    const int*   n2g = (const int*)d_in[9];

    const int N = in_sizes[0] / 64;   // 100000
    const int E = in_sizes[7];        // 1600000
    const int K = (N + BSZ - 1) >> KBSHIFT;   // 391 buckets
    const int nb = (N + 255) / 256;

    // ---- workspace carve-up (256B-aligned) ----
    char* p = (char*)d_ws;
    auto carve = [&](size_t bytes) {
        char* r = p;
        p += (bytes + 255) & ~(size_t)255;
        return r;
    };
    unsigned* A     = (unsigned*)carve((size_t)N * 64 * 2);  // m1 fp16 rows
    unsigned* B     = (unsigned*)carve((size_t)N * 64 * 2);  // m2 fp16 rows
    float* s3b      = (float*)carve((size_t)N * sizeof(float));
    float* w3s      = (float*)carve(65 * sizeof(float));
    int*   bcnt     = (int*)carve(KMAX * sizeof(int));
    int*   bbase    = (int*)carve((KMAX + 1) * sizeof(int));
    int*   bcursor  = (int*)carve(KMAX * sizeof(int));
    int*   rowptr   = (int*)carve((size_t)(N + 1) * sizeof(int));
    int*   esrc     = (int*)carve((size_t)E * sizeof(int));
    // packed pairs (E*4B = 6.4MB) alias B: dead before gather_gemm2 writes B.
    unsigned* pairs = (unsigned*)B;
    float* out      = (float*)d_out;

    const int gemm_blocks  = N / 16;
    const int gath_blocks  = (N + 7) / 8;           // 2 nodes/wave
    const int part_blocks  = (E + PCHUNK - 1) / PCHUNK;   // 512
    const int FUSED_BLOCKS = 2048;

    // ---- Layer 1 first (independent; also zeroes bcnt for bhist) ----
    gemm1_kernel<<<gemm_blocks, 256, 0, stream>>>(x, W1, b1, A, bcnt);

    // ---- CSR build: two-level counting sort ----
    bhist_kernel    <<<256, 256, 0, stream>>>(dst, bcnt, E, K);
    bscan_w3s_kernel<<<1, 512, 0, stream>>>(bcnt, bbase, bcursor, rowptr,
                                            W3, b3, w3s, K, N, E);
    partition_kernel<<<part_blocks, 512, 0, stream>>>(src, dst, bcursor, pairs, E, K);
    bucket_build_kernel<<<K, BSZ, 0, stream>>>(pairs, bbase, rowptr, esrc, N);

    // ---- Fused: gather-1 + tanh + GEMM-2 -> B (m2, fp16) ----
    gather_gemm2_kernel<<<FUSED_BLOCKS, 256, 0, stream>>>(
        (const uint4*)A, esrc, rowptr, W2, b2, B, N);

    // ---- Layer 3 collapsed + fused into gather 2 (also zeroes d_out) ----
    gather_s3_kernel<<<gath_blocks, 256, 0, stream>>>(
        (const uint4*)B, esrc, rowptr, w3s, s3b, out, N);

    graph_reduce_kernel<<<nb, 256, 0, stream>>>(s3b, esrc, rowptr, n2g, out, N);
}

// Round 9
// 271.476 us; speedup vs baseline: 11.0459x; 1.0332x over previous
//
#include <hip/hip_runtime.h>
#include <math.h>

#define NGRAPHS 8
#define KBSHIFT 8            // bucket = dst >> 8  (256 nodes per bucket)
#define BSZ 256              // nodes per bucket
#define KMAX 512             // >= K = ceil(N/BSZ) = 391
#define PCHUNK 3125          // edges per partition block (stage fits LDS)
// NOTE: partition packs (dst&255)<<23 | src -> requires src < 2^23 (N=100k ok)

typedef _Float16 h2 __attribute__((ext_vector_type(2)));

__device__ __forceinline__ h2 as_h2(unsigned u) { return __builtin_bit_cast(h2, u); }
__device__ __forceinline__ unsigned as_u(h2 h) { return __builtin_bit_cast(unsigned, h); }
__device__ __forceinline__ unsigned pkf16(float a, float b) {
    auto v = __builtin_amdgcn_cvt_pkrtz(a, b);   // v_cvt_pkrtz_f16_f32
    return __builtin_bit_cast(unsigned, v);
}
// fast tanh: 1 - 2/(e^{2x}+1); exact at +-inf ends, ~1e-6 rel err
__device__ __forceinline__ float ftanh(float x) {
    float t = __expf(2.0f * x);
    return 1.0f - 2.0f * __builtin_amdgcn_rcpf(t + 1.0f);
}
// fp32 accumulation of two edges' packed pair (gather_s3 path)
__device__ __forceinline__ void acc2(float& lo, float& hi, unsigned uA, unsigned uB) {
    const h2 ONES = {(_Float16)1.0f, (_Float16)1.0f};
    unsigned t0 = __builtin_amdgcn_perm(uB, uA, 0x05040100u);
    unsigned t1 = __builtin_amdgcn_perm(uB, uA, 0x07060302u);
    lo = __builtin_amdgcn_fdot2(as_h2(t0), ONES, lo, false);
    hi = __builtin_amdgcn_fdot2(as_h2(t1), ONES, hi, false);
}
__device__ __forceinline__ void acc1(float& lo, float& hi, unsigned u) {
    h2 hv = as_h2(u);
    lo += (float)hv.x;
    hi += (float)hv.y;
}

// ---------------------------------------------------------------------------
// GEMM: out[n][o] = sum_i f(in[n][i]) * W[o][i] + b[o]   (f = ftanh if TANH)
// INH: fp16 input rows. Output fp16. ZB: block 0 zeroes bcnt (for bhist).
// ---------------------------------------------------------------------------
template<bool TANH, bool INH, bool ZB>
__global__ __launch_bounds__(256) void gemm_kernel(
    const void* __restrict__ in_, const float* __restrict__ W,
    const float* __restrict__ bias, unsigned* __restrict__ out,
    int* __restrict__ bcnt)
{
    __shared__ float Wt[64 * 68];   // Wt[i*68 + o] = W[o][i]
    __shared__ float xs[16 * 65];
    const int t = threadIdx.x;
    const int node0 = blockIdx.x * 16;
    if (ZB && blockIdx.x == 0) { bcnt[t] = 0; bcnt[t + 256] = 0; }

    #pragma unroll
    for (int k = 0; k < 16; ++k) {
        int idx = k * 256 + t;
        int o = idx >> 6, i = idx & 63;
        Wt[i * 68 + o] = W[idx];
    }
    if (INH) {
        const unsigned* in = (const unsigned*)in_;
        #pragma unroll
        for (int k = 0; k < 2; ++k) {
            int idx = k * 256 + t;
            int nl = idx >> 5, ii = (idx & 31) * 2;
            h2 hv = as_h2(in[node0 * 32 + idx]);
            float a = (float)hv.x, b = (float)hv.y;
            if (TANH) { a = ftanh(a); b = ftanh(b); }
            xs[nl * 65 + ii] = a;
            xs[nl * 65 + ii + 1] = b;
        }
    } else {
        const float* in = (const float*)in_;
        #pragma unroll
        for (int k = 0; k < 4; ++k) {
            int idx = k * 256 + t;
            int nl = idx >> 6, i = idx & 63;
            float v = in[node0 * 64 + idx];
            if (TANH) v = ftanh(v);
            xs[nl * 65 + i] = v;
        }
    }
    __syncthreads();

    const int nl = t >> 4;
    const int o4 = t & 15;
    float4 acc = make_float4(0.f, 0.f, 0.f, 0.f);
    #pragma unroll
    for (int i = 0; i < 64; ++i) {
        float xv = xs[nl * 65 + i];
        float4 wv = *(const float4*)&Wt[i * 68 + o4 * 4];
        acc.x += xv * wv.x;
        acc.y += xv * wv.y;
        acc.z += xv * wv.z;
        acc.w += xv * wv.w;
    }
    float4 b4 = ((const float4*)bias)[o4];
    acc.x += b4.x; acc.y += b4.y; acc.z += b4.z; acc.w += b4.w;
    uint2 o;
    o.x = pkf16(acc.x, acc.y);
    o.y = pkf16(acc.z, acc.w);
    ((uint2*)out)[(node0 + nl) * 16 + o4] = o;
}

// ---------------------------------------------------------------------------
// Bucket histogram: bcnt[k] = #edges with dst>>8 == k.
// ---------------------------------------------------------------------------
__global__ __launch_bounds__(256) void bhist_kernel(
    const int* __restrict__ dst, int* __restrict__ bcnt, int E, int K)
{
    __shared__ int h[KMAX];
    int t = threadIdx.x;
    h[t] = 0; h[t + 256] = 0;
    __syncthreads();
    for (int e = blockIdx.x * 256 + t; e < E; e += gridDim.x * 256)
        atomicAdd(&h[dst[e] >> KBSHIFT], 1);
    __syncthreads();
    for (int k = t; k < K; k += 256)
        if (h[k] > 0) atomicAdd(&bcnt[k], h[k]);
}

// ---------------------------------------------------------------------------
// Exclusive scan of K (<=512) bucket counts -> bbase[0..K], bcursor=bbase.
// Fused: w3s[i] = colsum W3, w3s[64] = sum b3.
// ---------------------------------------------------------------------------
__global__ __launch_bounds__(512) void bscan_w3s_kernel(
    const int* __restrict__ bcnt, int* __restrict__ bbase,
    int* __restrict__ bcursor, int* __restrict__ rowptr,
    const float* __restrict__ W3, const float* __restrict__ b3,
    float* __restrict__ w3s, int K, int N, int E)
{
    __shared__ int tmp[512];
    int t = threadIdx.x;
    int v = (t < K) ? bcnt[t] : 0;
    tmp[t] = v;
    __syncthreads();
    #pragma unroll
    for (int off = 1; off < 512; off <<= 1) {
        int u = (t >= off) ? tmp[t - off] : 0;
        __syncthreads();
        tmp[t] += u;
        __syncthreads();
    }
    int excl = tmp[t] - v;
    if (t < K) { bbase[t] = excl; bcursor[t] = excl; }
    if (t == 0) { bbase[K] = E; rowptr[N] = E; }
    if (t < 64) {
        float s = 0.f;
        for (int o = 0; o < 64; ++o) s += W3[o * 64 + t];
        w3s[t] = s;
    }
    if (t == 64) {
        float bs = 0.f;
        for (int k = 0; k < 64; ++k) bs += b3[k];
        w3s[64] = bs;
    }
}

// ---------------------------------------------------------------------------
// Partition edges into buckets with LDS-staged, bucket-ordered output
// (coalesced per-bucket runs instead of 4B scatters).
// ---------------------------------------------------------------------------
__global__ __launch_bounds__(512) void partition_kernel(
    const int* __restrict__ src, const int* __restrict__ dst,
    int* __restrict__ bcursor, unsigned* __restrict__ pairs, int E, int K)
{
    __shared__ int h[512];
    __shared__ int sh[512];
    __shared__ int base[512];
    __shared__ int cur[512];
    __shared__ unsigned val[PCHUNK + 3];
    __shared__ unsigned short bk[PCHUNK + 3];
    const int t = threadIdx.x;
    const int lo = blockIdx.x * PCHUNK;
    int hi = lo + PCHUNK; if (hi > E) hi = E;
    const int cnt = hi - lo;

    h[t] = 0; cur[t] = 0;
    __syncthreads();
    for (int e = lo + t; e < hi; e += 512)
        atomicAdd(&h[dst[e] >> KBSHIFT], 1);
    __syncthreads();
    int v = h[t];
    int x = v;
    #pragma unroll
    for (int off = 1; off < 512; off <<= 1) {
        int u = (t >= off) ? h[t - off] : 0;
        __syncthreads();
        x += u;
        h[t] = x;
        __syncthreads();
    }
    sh[t] = x - v;
    base[t] = (t < K && v > 0) ? atomicAdd(&bcursor[t], v) : 0;
    __syncthreads();
    for (int e = lo + t; e < hi; e += 512) {
        int d = dst[e];
        int k = d >> KBSHIFT;
        int pos = atomicAdd(&cur[k], 1);
        int j = sh[k] + pos;
        val[j] = ((unsigned)(d & (BSZ - 1)) << 23) | (unsigned)src[e];
        bk[j] = (unsigned short)k;
    }
    __syncthreads();
    for (int j = t; j < cnt; j += 512) {
        int k = bk[j];
        pairs[base[k] + (j - sh[k])] = val[j];
    }
}

// ---------------------------------------------------------------------------
// Per-bucket CSR finalize: LDS hist -> scan -> rowptr + esrc scatter into
// the bucket's contiguous window.
// ---------------------------------------------------------------------------
__global__ __launch_bounds__(256) void bucket_build_kernel(
    const unsigned* __restrict__ pairs, const int* __restrict__ bbase,
    int* __restrict__ rowptr, int* __restrict__ esrc, int N)
{
    __shared__ int cnt[BSZ];
    __shared__ int tmp[BSZ];
    __shared__ int cur[BSZ];
    int k = blockIdx.x;
    int t = threadIdx.x;
    int ebase = bbase[k], eend = bbase[k + 1];

    cnt[t] = 0;
    __syncthreads();
    for (int e = ebase + t; e < eend; e += BSZ)
        atomicAdd(&cnt[pairs[e] >> 23], 1);
    __syncthreads();

    int v = cnt[t];
    tmp[t] = v;
    __syncthreads();
    #pragma unroll
    for (int off = 1; off < BSZ; off <<= 1) {
        int u = (t >= off) ? tmp[t - off] : 0;
        __syncthreads();
        tmp[t] += u;
        __syncthreads();
    }
    int excl = tmp[t] - v;
    cur[t] = excl;
    int n = (k << KBSHIFT) + t;
    if (n < N) rowptr[n] = ebase + excl;
    __syncthreads();

    for (int e = ebase + t; e < eend; e += BSZ) {
        unsigned p = pairs[e];
        int pos = atomicAdd(&cur[p >> 23], 1);
        esrc[ebase + pos] = (int)(p & 0x7fffffu);
    }
}

// ---------------------------------------------------------------------------
// Gather-aggregate, PACKED fp16 accumulation (v_pk_add_f16), 2 nodes/wave:
// out[n] = sum_inedges m[esrc[e]]. 1 VALU per edge-uint, packed xor-reduce,
// direct packed store (output is fp16 anyway). Accuracy: ~16-term fp16 sums,
// error damped by downstream tanh + W2 before reaching the output.
// ---------------------------------------------------------------------------
__global__ __launch_bounds__(256) void gather_agg_kernel(
    const uint4* __restrict__ m, const int* __restrict__ esrc,
    const int* __restrict__ rowptr, uint4* __restrict__ out, int N)
{
    const int t = threadIdx.x;
    const int n = blockIdx.x * 8 + (t >> 5);
    const int l32 = t & 31;
    const int sub = l32 >> 3, c = l32 & 7;
    h2 a0 = {0, 0}, a1 = {0, 0}, a2 = {0, 0}, a3 = {0, 0};
    if (n < N) {
        int beg = rowptr[n], end = rowptr[n + 1];
        int e = beg + sub;
        for (; e + 4 < end; e += 8) {
            int sA = esrc[e], sB = esrc[e + 4];
            uint4 vA = m[(size_t)sA * 8 + c];
            uint4 vB = m[(size_t)sB * 8 + c];
            a0 += as_h2(vA.x); a1 += as_h2(vA.y);
            a2 += as_h2(vA.z); a3 += as_h2(vA.w);
            a0 += as_h2(vB.x); a1 += as_h2(vB.y);
            a2 += as_h2(vB.z); a3 += as_h2(vB.w);
        }
        if (e < end) {
            uint4 vA = m[(size_t)esrc[e] * 8 + c];
            a0 += as_h2(vA.x); a1 += as_h2(vA.y);
            a2 += as_h2(vA.z); a3 += as_h2(vA.w);
        }
    }
    #pragma unroll
    for (int d = 8; d <= 16; d <<= 1) {
        a0 += as_h2(__shfl_xor(as_u(a0), d));
        a1 += as_h2(__shfl_xor(as_u(a1), d));
        a2 += as_h2(__shfl_xor(as_u(a2), d));
        a3 += as_h2(__shfl_xor(as_u(a3), d));
    }
    if (sub == 0 && n < N)
        out[(size_t)n * 8 + c] = make_uint4(as_u(a0), as_u(a1), as_u(a2), as_u(a3));
}

// ---------------------------------------------------------------------------
// Gather + collapsed layer 3, 2 nodes/wave, fp32 accumulation (accuracy-
// critical: error flows straight to output). Also zeroes d_out.
// ---------------------------------------------------------------------------
__global__ __launch_bounds__(256) void gather_s3_kernel(
    const uint4* __restrict__ m, const int* __restrict__ esrc,
    const int* __restrict__ rowptr, const float* __restrict__ w3s,
    float* __restrict__ s3, float* __restrict__ outz, int N)
{
    const int t = threadIdx.x;
    if (blockIdx.x == 0 && t < NGRAPHS) outz[t] = 0.f;
    const int n = blockIdx.x * 8 + (t >> 5);
    const int l32 = t & 31;
    const int sub = l32 >> 3, c = l32 & 7;
    float a[8] = {0.f,0.f,0.f,0.f,0.f,0.f,0.f,0.f};
    if (n < N) {
        int beg = rowptr[n], end = rowptr[n + 1];
        int e = beg + sub;
        for (; e + 4 < end; e += 8) {
            int sA = esrc[e], sB = esrc[e + 4];
            uint4 vA = m[(size_t)sA * 8 + c];
            uint4 vB = m[(size_t)sB * 8 + c];
            acc2(a[0], a[1], vA.x, vB.x);
            acc2(a[2], a[3], vA.y, vB.y);
            acc2(a[4], a[5], vA.z, vB.z);
            acc2(a[6], a[7], vA.w, vB.w);
        }
        if (e < end) {
            uint4 vA = m[(size_t)esrc[e] * 8 + c];
            acc1(a[0], a[1], vA.x);
            acc1(a[2], a[3], vA.y);
            acc1(a[4], a[5], vA.z);
            acc1(a[6], a[7], vA.w);
        }
    }
    #pragma unroll
    for (int d = 8; d <= 16; d <<= 1) {
        #pragma unroll
        for (int k = 0; k < 8; ++k) a[k] += __shfl_xor(a[k], d);
    }
    float4 w0 = ((const float4*)w3s)[c * 2];
    float4 w1 = ((const float4*)w3s)[c * 2 + 1];
    float partial = ftanh(a[0]) * w0.x + ftanh(a[1]) * w0.y
                  + ftanh(a[2]) * w0.z + ftanh(a[3]) * w0.w
                  + ftanh(a[4]) * w1.x + ftanh(a[5]) * w1.y
                  + ftanh(a[6]) * w1.z + ftanh(a[7]) * w1.w;
    partial += __shfl_xor(partial, 1);
    partial += __shfl_xor(partial, 2);
    partial += __shfl_xor(partial, 4);
    if (l32 == 0 && n < N) s3[n] = partial + w3s[64];
}

// ---------------------------------------------------------------------------
// per_graph[n2g[n]] += sum_{e in in(n)} s3[esrc[e]]   via CSR, LDS bins.
// ---------------------------------------------------------------------------
__global__ __launch_bounds__(256) void graph_reduce_kernel(
    const float* __restrict__ s3, const int* __restrict__ esrc,
    const int* __restrict__ rowptr, const int* __restrict__ n2g,
    float* __restrict__ out, int N)
{
    __shared__ float bins[NGRAPHS];
    int t = threadIdx.x;
    if (t < NGRAPHS) bins[t] = 0.f;
    __syncthreads();
    int n = blockIdx.x * 256 + t;
    if (n < N) {
        float acc = 0.f;
        for (int e = rowptr[n]; e < rowptr[n + 1]; ++e) acc += s3[esrc[e]];
        atomicAdd(&bins[n2g[n]], acc);
    }
    __syncthreads();
    if (t < NGRAPHS) unsafeAtomicAdd(&out[t], bins[t]);
}

// ---------------------------------------------------------------------------
extern "C" void kernel_launch(void* const* d_in, const int* in_sizes, int n_in,
                              void* d_out, int out_size, void* d_ws, size_t ws_size,
                              hipStream_t stream)
{
    const float* x   = (const float*)d_in[0];
    const float* W1  = (const float*)d_in[1];
    const float* b1  = (const float*)d_in[2];
    const float* W2  = (const float*)d_in[3];
    const float* b2  = (const float*)d_in[4];
    const float* W3  = (const float*)d_in[5];
    const float* b3  = (const float*)d_in[6];
    const int*   src = (const int*)d_in[7];
    const int*   dst = (const int*)d_in[8];
    const int*   n2g = (const int*)d_in[9];

    const int N = in_sizes[0] / 64;   // 100000
    const int E = in_sizes[7];        // 1600000
    const int K = (N + BSZ - 1) >> KBSHIFT;   // 391 buckets
    const int nb = (N + 255) / 256;

    // ---- workspace carve-up (256B-aligned) ----
    char* p = (char*)d_ws;
    auto carve = [&](size_t bytes) {
        char* r = p;
        p += (bytes + 255) & ~(size_t)255;
        return r;
    };
    unsigned* A     = (unsigned*)carve((size_t)N * 64 * 2);  // m1, later m2
    unsigned* B     = (unsigned*)carve((size_t)N * 64 * 2);  // pairs, later agg1
    float* s3b      = (float*)carve((size_t)N * sizeof(float));
    float* w3s      = (float*)carve(65 * sizeof(float));
    int*   bcnt     = (int*)carve(KMAX * sizeof(int));
    int*   bbase    = (int*)carve((KMAX + 1) * sizeof(int));
    int*   bcursor  = (int*)carve(KMAX * sizeof(int));
    int*   rowptr   = (int*)carve((size_t)(N + 1) * sizeof(int));
    int*   esrc     = (int*)carve((size_t)E * sizeof(int));
    unsigned* pairs = (unsigned*)B;   // dead before gather_agg writes B
    float* out      = (float*)d_out;

    const int gemm_blocks = N / 16;
    const int gath_blocks = (N + 7) / 8;           // 2 nodes/wave
    const int part_blocks = (E + PCHUNK - 1) / PCHUNK;   // 512

    // ---- Layer 1 first (independent; block 0 zeroes bcnt for bhist) ----
    gemm_kernel<false, false, true><<<gemm_blocks, 256, 0, stream>>>(x, W1, b1, A, bcnt);

    // ---- CSR build: two-level counting sort ----
    bhist_kernel    <<<256, 256, 0, stream>>>(dst, bcnt, E, K);
    bscan_w3s_kernel<<<1, 512, 0, stream>>>(bcnt, bbase, bcursor, rowptr,
                                            W3, b3, w3s, K, N, E);
    partition_kernel<<<part_blocks, 512, 0, stream>>>(src, dst, bcursor, pairs, E, K);
    bucket_build_kernel<<<K, BSZ, 0, stream>>>(pairs, bbase, rowptr, esrc, N);

    // ---- gather-1 (packed fp16 accumulate): A (m1) -> B (agg1) ----
    gather_agg_kernel<<<gath_blocks, 256, 0, stream>>>(
        (const uint4*)A, esrc, rowptr, (uint4*)B, N);

    // ---- GEMM-2 (ftanh fused on input): B (agg1) -> A (m2) ----
    gemm_kernel<true, true, false><<<gemm_blocks, 256, 0, stream>>>(B, W2, b2, A, nullptr);

    // ---- Layer 3 collapsed + fused into gather-2 (also zeroes d_out) ----
    gather_s3_kernel<<<gath_blocks, 256, 0, stream>>>(
        (const uint4*)A, esrc, rowptr, w3s, s3b, out, N);

    graph_reduce_kernel<<<nb, 256, 0, stream>>>(s3b, esrc, rowptr, n2g, out, N);
}